// Round 1
// baseline (2586.516 us; speedup 1.0000x reference)
//
#include <hip/hip_runtime.h>
#include <cmath>

#define T_ 1024
#define HID_ 2048
#define H_ 16
#define LQ_ 1536
#define LKV_ 512
#define DR_ 64
#define DN_ 128
#define DQ_ 192
#define DV_ 128
#define HI_ 16
#define DI_ 128
#define TOPK_ 256
#define NEGF (-1e30f)

__device__ __forceinline__ float wave_sum64(float v) {
#pragma unroll
  for (int off = 32; off; off >>= 1) v += __shfl_xor(v, off);
  return v;
}

// ---------------- GEMM: C = A * B^T  (B stored (N,K) row-major) ----------------
template<int BM,int BN,int BK,int TM,int TN>
__global__ __launch_bounds__(256) void gemm_bt_k(
    const float* __restrict__ A, int lda, long long sA,
    const float* __restrict__ B, int ldb, long long sB,
    float* __restrict__ C, int ldc, long long sC,
    int M, int N, int K)
{
  A += (long long)blockIdx.z * sA;
  B += (long long)blockIdx.z * sB;
  C += (long long)blockIdx.z * sC;
  __shared__ float As[BK][BM+4];
  __shared__ float Bs[BK][BN+4];
  const int bm = blockIdx.y*BM, bn = blockIdx.x*BN;
  const int tid = threadIdx.x;
  const int tc = tid % (BN/TN), tr = tid / (BN/TN);
  float acc[TM][TN] = {};
  for (int k0 = 0; k0 < K; k0 += BK) {
    for (int i = tid; i < BM*BK; i += 256) {
      int r = i / BK, c = i % BK;
      int gm = bm + r, gk = k0 + c;
      As[c][r] = (gm < M && gk < K) ? A[(long long)gm*lda + gk] : 0.f;
    }
    for (int i = tid; i < BN*BK; i += 256) {
      int r = i / BK, c = i % BK;
      int gn = bn + r, gk = k0 + c;
      Bs[c][r] = (gn < N && gk < K) ? B[(long long)gn*ldb + gk] : 0.f;
    }
    __syncthreads();
#pragma unroll
    for (int kk = 0; kk < BK; ++kk) {
      float a[TM], b[TN];
#pragma unroll
      for (int i = 0; i < TM; ++i) a[i] = As[kk][tr*TM+i];
#pragma unroll
      for (int j = 0; j < TN; ++j) b[j] = Bs[kk][tc*TN+j];
#pragma unroll
      for (int i = 0; i < TM; ++i)
#pragma unroll
        for (int j = 0; j < TN; ++j) acc[i][j] += a[i]*b[j];
    }
    __syncthreads();
  }
#pragma unroll
  for (int i = 0; i < TM; ++i) {
    int gm = bm + tr*TM + i;
    if (gm >= M) continue;
#pragma unroll
    for (int j = 0; j < TN; ++j) {
      int gn = bn + tc*TN + j;
      if (gn < N) C[(long long)gm*ldc + gn] = acc[i][j];
    }
  }
}

// ---------------- GEMM: C = A * B  (B stored (K,N) row-major) ----------------
template<int BM,int BN,int BK,int TM,int TN>
__global__ __launch_bounds__(256) void gemm_nn_k(
    const float* __restrict__ A, int lda, long long sA,
    const float* __restrict__ B, int ldb, long long sB,
    float* __restrict__ C, int ldc, long long sC,
    int M, int N, int K)
{
  A += (long long)blockIdx.z * sA;
  B += (long long)blockIdx.z * sB;
  C += (long long)blockIdx.z * sC;
  __shared__ float As[BK][BM+4];
  __shared__ float Bs[BK][BN+4];
  const int bm = blockIdx.y*BM, bn = blockIdx.x*BN;
  const int tid = threadIdx.x;
  const int tc = tid % (BN/TN), tr = tid / (BN/TN);
  float acc[TM][TN] = {};
  for (int k0 = 0; k0 < K; k0 += BK) {
    for (int i = tid; i < BM*BK; i += 256) {
      int r = i / BK, c = i % BK;
      int gm = bm + r, gk = k0 + c;
      As[c][r] = (gm < M && gk < K) ? A[(long long)gm*lda + gk] : 0.f;
    }
    for (int i = tid; i < BN*BK; i += 256) {
      int r = i % BN, c = i / BN;   // n fast -> coalesced
      int gn = bn + r, gk = k0 + c;
      Bs[c][r] = (gn < N && gk < K) ? B[(long long)gk*ldb + gn] : 0.f;
    }
    __syncthreads();
#pragma unroll
    for (int kk = 0; kk < BK; ++kk) {
      float a[TM], b[TN];
#pragma unroll
      for (int i = 0; i < TM; ++i) a[i] = As[kk][tr*TM+i];
#pragma unroll
      for (int j = 0; j < TN; ++j) b[j] = Bs[kk][tc*TN+j];
#pragma unroll
      for (int i = 0; i < TM; ++i)
#pragma unroll
        for (int j = 0; j < TN; ++j) acc[i][j] += a[i]*b[j];
    }
    __syncthreads();
  }
#pragma unroll
  for (int i = 0; i < TM; ++i) {
    int gm = bm + tr*TM + i;
    if (gm >= M) continue;
#pragma unroll
    for (int j = 0; j < TN; ++j) {
      int gn = bn + tc*TN + j;
      if (gn < N) C[(long long)gm*ldc + gn] = acc[i][j];
    }
  }
}

// ---------------- RMSNorm in-place over a row ----------------
__global__ __launch_bounds__(256) void rms_inplace_k(float* x, const float* __restrict__ g,
                                                     int C, int ld) {
  int t = blockIdx.x, tid = threadIdx.x;
  float* row = x + (long long)t*ld;
  float ss = 0.f;
  for (int i = tid; i < C; i += 256) { float v = row[i]; ss += v*v; }
  __shared__ float red[4];
  ss = wave_sum64(ss);
  if ((tid & 63) == 0) red[tid >> 6] = ss;
  __syncthreads();
  float tot = red[0] + red[1] + red[2] + red[3];
  float sc = rsqrtf(tot / (float)C + 1e-6f);
  for (int i = tid; i < C; i += 256) row[i] = row[i] * sc * g[i];
}

// ---------------- skv = [rms(ckv[:,:512])*g , rope(ckv[:,512:])] ; row T = 0 ----------------
__global__ __launch_bounds__(256) void skv_build_k(const float* __restrict__ ckv,
                                                   const float* __restrict__ g,
                                                   const float* __restrict__ cosb,
                                                   const float* __restrict__ sinb,
                                                   float* __restrict__ skv) {
  int t = blockIdx.x, tid = threadIdx.x;
  float* out = skv + (long long)t*576;
  if (t == T_) { for (int i = tid; i < 576; i += 256) out[i] = 0.f; return; }
  const float* row = ckv + (long long)t*576;
  float ss = 0.f;
  for (int i = tid; i < 512; i += 256) { float v = row[i]; ss += v*v; }
  __shared__ float red[4];
  ss = wave_sum64(ss);
  if ((tid & 63) == 0) red[tid >> 6] = ss;
  __syncthreads();
  float tot = red[0] + red[1] + red[2] + red[3];
  float sc = rsqrtf(tot / 512.f + 1e-6f);
  for (int i = tid; i < 512; i += 256) out[i] = row[i] * sc * g[i];
  if (tid < 64) {
    int j = tid, j2 = tid & 31;
    float c = cosb[t*64 + j], s = sinb[t*64 + j];
    float a = row[512 + 2*j2], b = row[512 + 2*j2 + 1];
    out[512 + j] = (j < 32) ? (a*c - b*s) : (a*s + b*c);
  }
}

// ---------------- rope in-place on qi heads ----------------
__global__ __launch_bounds__(64) void rope_qi_k(float* qi, const float* __restrict__ cosb,
                                                const float* __restrict__ sinb) {
  int b = blockIdx.x, t = b >> 4, j = threadIdx.x, j2 = j & 31;
  float* x = qi + (long long)b * DI_;
  float c = cosb[t*64 + j], s = sinb[t*64 + j];
  float a = x[2*j2], bb = x[2*j2 + 1];      // single wave: loads precede the store
  float o = (j < 32) ? (a*c - bb*s) : (a*s + bb*c);
  x[j] = o;
}

// ---------------- ki: LayerNorm then rope first 64, in-place ----------------
__global__ __launch_bounds__(128) void ki_ln_rope_k(float* kbuf, const float* __restrict__ w,
                                                    const float* __restrict__ bia,
                                                    const float* __restrict__ cosb,
                                                    const float* __restrict__ sinb) {
  int t = blockIdx.x, i = threadIdx.x;
  float* row = kbuf + (long long)t * DI_;
  float x = row[i];
  __shared__ float red[2];
  float s1 = wave_sum64(x);
  if ((i & 63) == 0) red[i >> 6] = s1;
  __syncthreads();
  float mean = (red[0] + red[1]) / 128.f;
  float d = x - mean;
  __syncthreads();
  float s2 = wave_sum64(d*d);
  if ((i & 63) == 0) red[i >> 6] = s2;
  __syncthreads();
  float var = (red[0] + red[1]) / 128.f;
  float y = d * rsqrtf(var + 1e-6f) * w[i] + bia[i];
  __shared__ float rowl[128];
  rowl[i] = y;
  __syncthreads();
  float outv = y;
  if (i < 64) {
    int j2 = i & 31;
    float c = cosb[t*64 + i], s = sinb[t*64 + i];
    float a = rowl[2*j2], b = rowl[2*j2 + 1];
    outv = (i < 32) ? (a*c - b*s) : (a*s + b*c);
  }
  row[i] = outv;
}

// ---------------- rope q_full tail -> sq[...,512:576] ----------------
__global__ __launch_bounds__(64) void rope_q_sq_k(const float* __restrict__ qfull,
                                                  const float* __restrict__ cosb,
                                                  const float* __restrict__ sinb,
                                                  float* __restrict__ sq) {
  int b = blockIdx.x, t = b >> 4, h = b & 15, j = threadIdx.x, j2 = j & 31;
  const float* x = qfull + (long long)t*3072 + h*192 + 128;
  float c = cosb[t*64 + j], s = sinb[t*64 + j];
  float a = x[2*j2], bb = x[2*j2 + 1];
  float o = (j < 32) ? (a*c - bb*s) : (a*s + bb*c);
  sq[((long long)t*H_ + h)*576 + 512 + j] = o;
}

// ---------------- indexer scores + exact fp32 top-256 (bitonic) ----------------
__global__ __launch_bounds__(256) void score_topk_k(
    const float* __restrict__ qi, const float* __restrict__ ki,
    const float* __restrict__ wproj, const int* __restrict__ ks,
    const int* __restrict__ ke, int* __restrict__ indices)
{
  int t = blockIdx.x, tid = threadIdx.x;
  __shared__ float s_qi[HI_*DI_];
  __shared__ float s_w[HI_];
  __shared__ float s_score[T_];
  __shared__ int s_idx[T_];
  for (int i = tid; i < HI_*DI_; i += 256) s_qi[i] = qi[(long long)t*HI_*DI_ + i];
  if (tid < HI_) s_w[tid] = wproj[t*HI_ + tid] * 0.022097086912079608f; // DI^-.5 * HI^-.5
  __syncthreads();
  int lo = ks[t], hi = ke[t];
  for (int s = tid; s < T_; s += 256) {
    const float4* kr = (const float4*)(ki + (long long)s * DI_);
    float dots[HI_] = {};
    for (int d4 = 0; d4 < DI_/4; ++d4) {
      float4 v = kr[d4];
      int d = d4*4;
#pragma unroll
      for (int h = 0; h < HI_; ++h) {
        const float* q = s_qi + h*DI_ + d;
        dots[h] += q[0]*v.x + q[1]*v.y + q[2]*v.z + q[3]*v.w;
      }
    }
    float sc = 0.f;
#pragma unroll
    for (int h = 0; h < HI_; ++h) sc += fmaxf(dots[h], 0.f) * s_w[h];
    bool valid = (s >= lo) && (s <= hi);
    s_score[s] = valid ? sc : NEGF;
    s_idx[s] = s;
  }
  __syncthreads();
  // ascending bitonic sort of 1024 (score,idx) pairs; top-k set is order-invariant downstream
  for (int k = 2; k <= T_; k <<= 1) {
    for (int j = k >> 1; j > 0; j >>= 1) {
      for (int i = tid; i < T_; i += 256) {
        int l = i ^ j;
        if (l > i) {
          float a = s_score[i], b = s_score[l];
          bool up = ((i & k) == 0);
          if (up ? (a > b) : (a < b)) {
            s_score[i] = b; s_score[l] = a;
            int ti = s_idx[i]; s_idx[i] = s_idx[l]; s_idx[l] = ti;
          }
        }
      }
      __syncthreads();
    }
  }
  if (tid < TOPK_) {
    float v = s_score[T_ - 1 - tid];
    int id = s_idx[T_ - 1 - tid];
    indices[t*TOPK_ + tid] = (v <= NEGF*0.5f) ? T_ : id;
  }
}

// ---------------- gathered attention: logits -> softmax -> PV ----------------
__global__ __launch_bounds__(256) void attn_k(
    const float* __restrict__ sq, const float* __restrict__ skv,
    const int* __restrict__ indices, float* __restrict__ attn_out)
{
  int t = blockIdx.x, tid = threadIdx.x;
  __shared__ float s_sq[H_*576];
  __shared__ float s_p[H_][TOPK_];
  __shared__ int s_ind[TOPK_];
  for (int i = tid; i < H_*576; i += 256) s_sq[i] = sq[(long long)t*H_*576 + i];
  s_ind[tid] = indices[t*TOPK_ + tid];
  __syncthreads();
  { // logits: one key per thread
    int row = s_ind[tid];
    const float4* kv4 = (const float4*)(skv + (long long)row * 576);
    float acc[H_] = {};
    for (int d4 = 0; d4 < 144; ++d4) {
      float4 v = kv4[d4];
      int d = d4*4;
#pragma unroll
      for (int h = 0; h < H_; ++h) {
        const float* q = s_sq + h*576 + d;
        acc[h] += q[0]*v.x + q[1]*v.y + q[2]*v.z + q[3]*v.w;
      }
    }
    const float scale = 0.07216878364870322f; // 192^-0.5
    bool masked = (row == T_);
#pragma unroll
    for (int h = 0; h < H_; ++h) s_p[h][tid] = masked ? NEGF : acc[h]*scale;
  }
  __syncthreads();
  int wave = tid >> 6, lane = tid & 63;
  for (int h = wave*4; h < wave*4 + 4; ++h) {
    float m = -3.4e38f;
    for (int j = lane; j < TOPK_; j += 64) m = fmaxf(m, s_p[h][j]);
#pragma unroll
    for (int off = 32; off; off >>= 1) m = fmaxf(m, __shfl_xor(m, off));
    float sum = 0.f;
    for (int j = lane; j < TOPK_; j += 64) {
      float e = __expf(s_p[h][j] - m);
      s_p[h][j] = e; sum += e;
    }
    sum = wave_sum64(sum);
    float inv = 1.f / sum;
    for (int j = lane; j < TOPK_; j += 64) s_p[h][j] *= inv;
  }
  __syncthreads();
  // PV: two k-columns per thread
  float a0[H_] = {}, a1[H_] = {};
  for (int j = 0; j < TOPK_; ++j) {
    const float* kv = skv + (long long)s_ind[j] * 576;
    float v0 = kv[tid], v1 = kv[tid + 256];
#pragma unroll
    for (int h = 0; h < H_; ++h) { float p = s_p[h][j]; a0[h] += p*v0; a1[h] += p*v1; }
  }
#pragma unroll
  for (int h = 0; h < H_; ++h) {
    attn_out[((long long)t*H_ + h)*512 + tid] = a0[h];
    attn_out[((long long)t*H_ + h)*512 + tid + 256] = a1[h];
  }
}

extern "C" void kernel_launch(void* const* d_in, const int* in_sizes, int n_in,
                              void* d_out, int out_size, void* d_ws, size_t ws_size,
                              hipStream_t stream) {
  const float* hidden  = (const float*)d_in[0];
  const float* cosb    = (const float*)d_in[1];
  const float* sinb    = (const float*)d_in[2];
  const int*   ks      = (const int*)d_in[3];
  const int*   ke      = (const int*)d_in[4];
  const float* w_qa    = (const float*)d_in[5];
  const float* g_qa    = (const float*)d_in[6];
  const float* w_qb    = (const float*)d_in[7];
  const float* w_kva   = (const float*)d_in[8];
  const float* g_kva   = (const float*)d_in[9];
  const float* w_kvb   = (const float*)d_in[10];
  const float* w_o     = (const float*)d_in[11];
  const float* i_wqb   = (const float*)d_in[12];
  const float* i_wk    = (const float*)d_in[13];
  const float* i_ln_w  = (const float*)d_in[14];
  const float* i_ln_b  = (const float*)d_in[15];
  const float* i_wproj = (const float*)d_in[16];
  float* out = (float*)d_out;
  (void)in_sizes; (void)n_in; (void)out_size; (void)ws_size;

  // workspace layout (floats). Lifetime-overlapped: attn reuses [0, 8388608);
  // obuf reuses sq's region (sq dead after attn).
  float* ws     = (float*)d_ws;
  float* q_lat  = ws + 0;          // 1,572,864  (T,1536)        dead after q_full gemm
  float* qi     = ws + 1572864;    // 2,097,152  (T,16,128)      dead after topk
  float* qfull  = ws + 3670016;    // 3,145,728  (T,3072)        dead after q_abs
  float* ckv    = ws + 6815744;    //   589,824  (T,576)         dead after skv build
  float* kib    = ws + 7405568;    //   131,072  (T,128)         dead after topk
  float* wbuf   = ws + 7536640;    //    16,384  (T,16)          dead after topk
  float* attn   = ws + 0;          // 8,388,608  (T,16,512)      written after all the above die
  float* skv    = ws + 8388608;    //   590,400  (T+1,576)
  int*   idxb   = (int*)(ws + 8979008); // 262,144 (T,256)
  float* sqb    = ws + 9241152;    // 9,437,184  (T,16,576)      dead after attn
  float* obuf   = ws + 9241152;    // 2,097,152  (T,2048)        reuses sq region
  // total: 18,678,336 floats = 74.7 MB

  dim3 blk(256);
  // 1. q_lat = hidden @ w_qa.T
  gemm_bt_k<64,64,16,4,4><<<dim3(24,16,1), blk, 0, stream>>>(
      hidden, HID_, 0, w_qa, HID_, 0, q_lat, LQ_, 0, T_, LQ_, HID_);
  // 2. RMS(q_lat)*g_qa
  rms_inplace_k<<<T_, blk, 0, stream>>>(q_lat, g_qa, LQ_, LQ_);
  // 3. ckv = hidden @ w_kva.T
  gemm_bt_k<64,64,16,4,4><<<dim3(9,16,1), blk, 0, stream>>>(
      hidden, HID_, 0, w_kva, HID_, 0, ckv, 576, 0, T_, 576, HID_);
  // 4. skv = [rms*g, rope] + zero row
  skv_build_k<<<T_+1, blk, 0, stream>>>(ckv, g_kva, cosb, sinb, skv);
  // 5. qi = q_lat @ i_wqb.T
  gemm_bt_k<64,64,16,4,4><<<dim3(32,16,1), blk, 0, stream>>>(
      q_lat, LQ_, 0, i_wqb, LQ_, 0, qi, HI_*DI_, 0, T_, HI_*DI_, LQ_);
  // 6. rope qi heads in place
  rope_qi_k<<<T_*HI_, dim3(64), 0, stream>>>(qi, cosb, sinb);
  // 7. ki = hidden @ i_wk.T
  gemm_bt_k<64,64,16,4,4><<<dim3(2,16,1), blk, 0, stream>>>(
      hidden, HID_, 0, i_wk, HID_, 0, kib, DI_, 0, T_, DI_, HID_);
  // 8. LN + rope on ki
  ki_ln_rope_k<<<T_, dim3(128), 0, stream>>>(kib, i_ln_w, i_ln_b, cosb, sinb);
  // 9. w = hidden @ i_wproj.T
  gemm_bt_k<64,64,16,4,4><<<dim3(1,16,1), blk, 0, stream>>>(
      hidden, HID_, 0, i_wproj, HID_, 0, wbuf, HI_, 0, T_, HI_, HID_);
  // 10. indexer scores + top-256
  score_topk_k<<<T_, blk, 0, stream>>>(qi, kib, wbuf, ks, ke, idxb);
  // 11. q_full = q_lat @ w_qb.T
  gemm_bt_k<64,64,16,4,4><<<dim3(48,16,1), blk, 0, stream>>>(
      q_lat, LQ_, 0, w_qb, LQ_, 0, qfull, H_*DQ_, 0, T_, H_*DQ_, LQ_);
  // 12. rope(q_full rope part) -> sq[...,512:576]
  rope_q_sq_k<<<T_*H_, dim3(64), 0, stream>>>(qfull, cosb, sinb, sqb);
  // 13. q_abs = q_nope @ w_kn (per head) -> sq[...,0:512]
  gemm_nn_k<64,64,16,4,4><<<dim3(8,16,16), blk, 0, stream>>>(
      qfull, H_*DQ_, 192, w_kvb, LKV_, 256LL*512, sqb, H_*576, 576, T_, LKV_, DN_);
  // 14. gathered attention
  attn_k<<<T_, blk, 0, stream>>>(sqb, skv, idxb, attn);
  // 15. o = attn_out @ w_v.T (per head)
  gemm_bt_k<64,64,16,4,4><<<dim3(2,16,16), blk, 0, stream>>>(
      attn, H_*LKV_, 512, w_kvb + 128LL*512, LKV_, 256LL*512, obuf, H_*DV_, 128, T_, DV_, LKV_);
  // 16. final = o @ w_o.T
  gemm_bt_k<64,64,16,4,4><<<dim3(32,16,1), blk, 0, stream>>>(
      obuf, H_*DV_, 0, w_o, H_*DV_, 0, out, HID_, 0, T_, HID_, H_*DV_);
}

// Round 4
// 978.126 us; speedup vs baseline: 2.6444x; 2.6444x over previous
//
#include <hip/hip_runtime.h>
#include <hip/hip_bf16.h>
#include <cmath>

#define T_ 1024
#define HID_ 2048
#define H_ 16
#define LQ_ 1536
#define LKV_ 512
#define DR_ 64
#define DN_ 128
#define DQ_ 192
#define DV_ 128
#define HI_ 16
#define DI_ 128
#define TOPK_ 256
#define NEGF (-1e30f)

typedef short bfrag_t __attribute__((ext_vector_type(8)));   // 8 bf16 = 4 VGPRs
typedef float f32x4 __attribute__((ext_vector_type(4)));

__device__ __forceinline__ float wave_sum64(float v) {
#pragma unroll
  for (int off = 32; off; off >>= 1) v += __shfl_xor(v, off);
  return v;
}

// ================= bf16 MFMA GEMM: C = A @ B^T  (verified structure, R3) =================
template<typename CT>
__global__ __launch_bounds__(256) void gemm_bf_k(
    const short* __restrict__ A, int lda, long long sA,
    const short* __restrict__ B, int ldb, long long sB,
    CT* __restrict__ C, int ldc, long long sC,
    int Nout, int K)
{
  __shared__ short As[128 * 32];
  __shared__ short Bs[128 * 32];
  A += (long long)blockIdx.z * sA;
  B += (long long)blockIdx.z * sB;
  C += (long long)blockIdx.z * sC;
  const int tid = threadIdx.x;
  const int bm = blockIdx.y * 128, bn = blockIdx.x * 128;
  const int wave = tid >> 6, lane = tid & 63;
  const int wm = (wave >> 1) * 64, wn = (wave & 1) * 64;
  const int sr = tid >> 2;
  const int scol = (tid & 3) * 8;
  const int m0 = lane & 15, koff = (lane >> 4) * 8;
  f32x4 acc[4][4] = {};
  const short* ga = A + (long long)(bm + sr) * lda + scol;
  const short* gb = B + (long long)(bn + sr) * ldb + scol;
  short* la = As + tid * 8;
  short* lb = Bs + tid * 8;
  for (int kk = 0; kk < K; kk += 32) {
    __builtin_amdgcn_global_load_lds((const __attribute__((address_space(1))) void*)(ga),
                                     (__attribute__((address_space(3))) void*)(la), 16, 0, 0);
    __builtin_amdgcn_global_load_lds((const __attribute__((address_space(1))) void*)(ga + 64 * lda),
                                     (__attribute__((address_space(3))) void*)(la + 2048), 16, 0, 0);
    __builtin_amdgcn_global_load_lds((const __attribute__((address_space(1))) void*)(gb),
                                     (__attribute__((address_space(3))) void*)(lb), 16, 0, 0);
    __builtin_amdgcn_global_load_lds((const __attribute__((address_space(1))) void*)(gb + 64 * ldb),
                                     (__attribute__((address_space(3))) void*)(lb + 2048), 16, 0, 0);
    ga += 32; gb += 32;
    __syncthreads();
    bfrag_t af[4], bfv[4];
#pragma unroll
    for (int i = 0; i < 4; ++i)
      af[i] = *(const bfrag_t*)(As + (wm + i * 16 + m0) * 32 + koff);
#pragma unroll
    for (int j = 0; j < 4; ++j)
      bfv[j] = *(const bfrag_t*)(Bs + (wn + j * 16 + m0) * 32 + koff);
#pragma unroll
    for (int i = 0; i < 4; ++i)
#pragma unroll
      for (int j = 0; j < 4; ++j)
        acc[i][j] = __builtin_amdgcn_mfma_f32_16x16x32_bf16(af[i], bfv[j], acc[i][j], 0, 0, 0);
    __syncthreads();
  }
  const int cr = (lane >> 4) * 4, cc = lane & 15;
#pragma unroll
  for (int i = 0; i < 4; ++i) {
    int row = bm + wm + i * 16 + cr;
#pragma unroll
    for (int j = 0; j < 4; ++j) {
      int col = bn + wn + j * 16 + cc;
      if (col < Nout) {
#pragma unroll
        for (int r = 0; r < 4; ++r)
          C[(long long)(row + r) * ldc + col] = (CT)(acc[i][j][r]);
      }
    }
  }
}

// ====== bf16x3 split GEMM: C = (Ah+Al) @ (Bh+Bl)^T ~= AhBh + AhBl + AlBh (fp32-accurate) ======
__global__ __launch_bounds__(256) void gemm3_k(
    const short* __restrict__ Ah, const short* __restrict__ Al, int lda,
    const short* __restrict__ Bh, const short* __restrict__ Bl, int ldb,
    float* __restrict__ C, int ldc, int Nout, int K)
{
  __shared__ short Ahs[128 * 32];
  __shared__ short Als[128 * 32];
  __shared__ short Bhs[128 * 32];
  __shared__ short Bls[128 * 32];
  const int tid = threadIdx.x;
  const int bm = blockIdx.y * 128, bn = blockIdx.x * 128;
  const int wave = tid >> 6, lane = tid & 63;
  const int wm = (wave >> 1) * 64, wn = (wave & 1) * 64;
  const int sr = tid >> 2;
  const int scol = (tid & 3) * 8;
  const int m0 = lane & 15, koff = (lane >> 4) * 8;
  f32x4 acc[4][4] = {};
  const short* gah = Ah + (long long)(bm + sr) * lda + scol;
  const short* gal = Al + (long long)(bm + sr) * lda + scol;
  const short* gbh = Bh + (long long)(bn + sr) * ldb + scol;
  const short* gbl = Bl + (long long)(bn + sr) * ldb + scol;
  short* lah = Ahs + tid * 8;
  short* lal = Als + tid * 8;
  short* lbh = Bhs + tid * 8;
  short* lbl = Bls + tid * 8;
  for (int kk = 0; kk < K; kk += 32) {
#define GLL(g, l) __builtin_amdgcn_global_load_lds((const __attribute__((address_space(1))) void*)(g), \
                                     (__attribute__((address_space(3))) void*)(l), 16, 0, 0)
    GLL(gah, lah); GLL(gah + 64 * lda, lah + 2048);
    GLL(gal, lal); GLL(gal + 64 * lda, lal + 2048);
    GLL(gbh, lbh); GLL(gbh + 64 * ldb, lbh + 2048);
    GLL(gbl, lbl); GLL(gbl + 64 * ldb, lbl + 2048);
#undef GLL
    gah += 32; gal += 32; gbh += 32; gbl += 32;
    __syncthreads();
    bfrag_t afh[4], afl[4], bfh[4], bfl[4];
#pragma unroll
    for (int i = 0; i < 4; ++i) {
      afh[i] = *(const bfrag_t*)(Ahs + (wm + i * 16 + m0) * 32 + koff);
      afl[i] = *(const bfrag_t*)(Als + (wm + i * 16 + m0) * 32 + koff);
    }
#pragma unroll
    for (int j = 0; j < 4; ++j) {
      bfh[j] = *(const bfrag_t*)(Bhs + (wn + j * 16 + m0) * 32 + koff);
      bfl[j] = *(const bfrag_t*)(Bls + (wn + j * 16 + m0) * 32 + koff);
    }
#pragma unroll
    for (int i = 0; i < 4; ++i)
#pragma unroll
      for (int j = 0; j < 4; ++j) {
        acc[i][j] = __builtin_amdgcn_mfma_f32_16x16x32_bf16(afh[i], bfh[j], acc[i][j], 0, 0, 0);
        acc[i][j] = __builtin_amdgcn_mfma_f32_16x16x32_bf16(afh[i], bfl[j], acc[i][j], 0, 0, 0);
        acc[i][j] = __builtin_amdgcn_mfma_f32_16x16x32_bf16(afl[i], bfh[j], acc[i][j], 0, 0, 0);
      }
    __syncthreads();
  }
  const int cr = (lane >> 4) * 4, cc = lane & 15;
#pragma unroll
  for (int i = 0; i < 4; ++i) {
    int row = bm + wm + i * 16 + cr;
#pragma unroll
    for (int j = 0; j < 4; ++j) {
      int col = bn + wn + j * 16 + cc;
      if (col < Nout) {
#pragma unroll
        for (int r = 0; r < 4; ++r)
          C[(long long)(row + r) * ldc + col] = acc[i][j][r];
      }
    }
  }
}

// ================= casts / decompose =================
__global__ __launch_bounds__(256) void cast_bf16_k(const float* __restrict__ src,
                                                   __hip_bfloat16* __restrict__ dst, int n4) {
  int i = blockIdx.x * 256 + threadIdx.x;
  if (i >= n4) return;
  float4 v = ((const float4*)src)[i];
  union { ushort4 u; __hip_bfloat16 h[4]; } o;
  o.h[0] = __float2bfloat16(v.x); o.h[1] = __float2bfloat16(v.y);
  o.h[2] = __float2bfloat16(v.z); o.h[3] = __float2bfloat16(v.w);
  ((ushort4*)dst)[i] = o.u;
}

__global__ __launch_bounds__(256) void decomp_k(const float* __restrict__ src,
                                                __hip_bfloat16* __restrict__ hi,
                                                __hip_bfloat16* __restrict__ lo, int n4) {
  int i = blockIdx.x * 256 + threadIdx.x;
  if (i >= n4) return;
  float4 v = ((const float4*)src)[i];
  float f[4] = {v.x, v.y, v.z, v.w};
  union { ushort4 u; __hip_bfloat16 h[4]; } oh, ol;
#pragma unroll
  for (int j = 0; j < 4; ++j) {
    __hip_bfloat16 h = __float2bfloat16(f[j]);
    oh.h[j] = h;
    ol.h[j] = __float2bfloat16(f[j] - __bfloat162float(h));
  }
  ((ushort4*)hi)[i] = oh.u;
  ((ushort4*)lo)[i] = ol.u;
}

__global__ __launch_bounds__(256) void cast_pad_k(const float* __restrict__ src,
                                                  __hip_bfloat16* __restrict__ dst,
                                                  int N, int K4, int Npad) {
  int i = blockIdx.x * 256 + threadIdx.x;
  if (i >= Npad * K4) return;
  int r = i / K4;
  float4 v = make_float4(0.f, 0.f, 0.f, 0.f);
  if (r < N) v = ((const float4*)src)[i];
  union { ushort4 u; __hip_bfloat16 h[4]; } o;
  o.h[0] = __float2bfloat16(v.x); o.h[1] = __float2bfloat16(v.y);
  o.h[2] = __float2bfloat16(v.z); o.h[3] = __float2bfloat16(v.w);
  ((ushort4*)dst)[i] = o.u;
}

// w_kn transposed-cast: dst[h][k][d] = w_kvb[(h*256+d)*512+k]
__global__ __launch_bounds__(256) void wkn_t_k(const float* __restrict__ wkvb,
                                               __hip_bfloat16* __restrict__ dst) {
  int i = blockIdx.x * 256 + threadIdx.x;
  int d = i & 127, k = (i >> 7) & 511, h = i >> 16;
  dst[i] = __float2bfloat16(wkvb[((h * 256 + d) << 9) + k]);
}

// w_v compact-cast: dst[h][dv][k] = w_kvb[(h*256+128+dv)*512+k]
__global__ __launch_bounds__(256) void wv_cast_k(const float* __restrict__ wkvb,
                                                 __hip_bfloat16* __restrict__ dst) {
  int i = blockIdx.x * 256 + threadIdx.x;
  int k = i & 511, dv = (i >> 9) & 127, h = i >> 16;
  dst[i] = __float2bfloat16(wkvb[((h * 256 + 128 + dv) << 9) + k]);
}

// ================= RMSNorm in-place (fp32) =================
__global__ __launch_bounds__(256) void rms_inplace_k(float* x, const float* __restrict__ g,
                                                     int C) {
  int t = blockIdx.x, tid = threadIdx.x;
  float* row = x + (long long)t * C;
  float ss = 0.f;
  for (int i = tid; i < C; i += 256) { float v = row[i]; ss += v * v; }
  __shared__ float red[4];
  ss = wave_sum64(ss);
  if ((tid & 63) == 0) red[tid >> 6] = ss;
  __syncthreads();
  float sc = rsqrtf((red[0] + red[1] + red[2] + red[3]) / (float)C + 1e-6f);
  for (int i = tid; i < C; i += 256) row[i] = row[i] * sc * g[i];
}

// ================= skv build =================
__global__ __launch_bounds__(256) void skv_build_k(const float* __restrict__ ckv,
                                                   const float* __restrict__ g,
                                                   const float* __restrict__ cosb,
                                                   const float* __restrict__ sinb,
                                                   float* __restrict__ skv) {
  int t = blockIdx.x, tid = threadIdx.x;
  float* out = skv + (long long)t * 576;
  if (t == T_) { for (int i = tid; i < 576; i += 256) out[i] = 0.f; return; }
  const float* row = ckv + (long long)t * 576;
  float ss = 0.f;
  for (int i = tid; i < 512; i += 256) { float v = row[i]; ss += v * v; }
  __shared__ float red[4];
  ss = wave_sum64(ss);
  if ((tid & 63) == 0) red[tid >> 6] = ss;
  __syncthreads();
  float sc = rsqrtf((red[0] + red[1] + red[2] + red[3]) / 512.f + 1e-6f);
  for (int i = tid; i < 512; i += 256) out[i] = row[i] * sc * g[i];
  if (tid < 64) {
    int j = tid, j2 = tid & 31;
    float c = cosb[t * 64 + j], s = sinb[t * 64 + j];
    float a = row[512 + 2 * j2], b = row[512 + 2 * j2 + 1];
    out[512 + j] = (j < 32) ? (a * c - b * s) : (a * s + b * c);
  }
}

// ================= rope in-place on qi heads (fp32) =================
__global__ __launch_bounds__(64) void rope_qi_k(float* qi, const float* __restrict__ cosb,
                                                const float* __restrict__ sinb) {
  int b = blockIdx.x, t = b >> 4, j = threadIdx.x, j2 = j & 31;
  float* x = qi + (long long)b * DI_;
  float c = cosb[t * 64 + j], s = sinb[t * 64 + j];
  float a = x[2 * j2], bb = x[2 * j2 + 1];
  float o = (j < 32) ? (a * c - bb * s) : (a * s + bb * c);
  x[j] = o;
}

// ================= ki: LayerNorm then rope first 64, in-place (fp32) =================
__global__ __launch_bounds__(128) void ki_ln_rope_k(float* kbuf, const float* __restrict__ w,
                                                    const float* __restrict__ bia,
                                                    const float* __restrict__ cosb,
                                                    const float* __restrict__ sinb) {
  int t = blockIdx.x, i = threadIdx.x;
  float* row = kbuf + (long long)t * DI_;
  float x = row[i];
  __shared__ float red[2];
  float s1 = wave_sum64(x);
  if ((i & 63) == 0) red[i >> 6] = s1;
  __syncthreads();
  float mean = (red[0] + red[1]) / 128.f;
  float d = x - mean;
  __syncthreads();
  float s2 = wave_sum64(d * d);
  if ((i & 63) == 0) red[i >> 6] = s2;
  __syncthreads();
  float var = (red[0] + red[1]) / 128.f;
  float y = d * rsqrtf(var + 1e-6f) * w[i] + bia[i];
  __shared__ float rowl[128];
  rowl[i] = y;
  __syncthreads();
  float outv = y;
  if (i < 64) {
    int j2 = i & 31;
    float c = cosb[t * 64 + i], s = sinb[t * 64 + i];
    float a = rowl[2 * j2], b = rowl[2 * j2 + 1];
    outv = (i < 32) ? (a * c - b * s) : (a * s + b * c);
  }
  row[i] = outv;
}

// ================= rope q_full tail (bf16 in) -> sq[...,512:576] fp32 =================
__global__ __launch_bounds__(64) void rope_q_sq_k(const __hip_bfloat16* __restrict__ qfull,
                                                  const float* __restrict__ cosb,
                                                  const float* __restrict__ sinb,
                                                  float* __restrict__ sq) {
  int b = blockIdx.x, t = b >> 4, h = b & 15, j = threadIdx.x, j2 = j & 31;
  const __hip_bfloat16* x = qfull + (long long)t * 3072 + h * 192 + 128;
  float c = cosb[t * 64 + j], s = sinb[t * 64 + j];
  float a = __bfloat162float(x[2 * j2]), bb = __bfloat162float(x[2 * j2 + 1]);
  float o = (j < 32) ? (a * c - bb * s) : (a * s + bb * c);
  sq[((long long)t * H_ + h) * 576 + 512 + j] = o;
}

// ================= w = hidden @ i_wproj.T (fp32, wave-per-row) =================
__global__ __launch_bounds__(256) void wproj_k(const float* __restrict__ hidden,
                                               const float* __restrict__ wp,
                                               float* __restrict__ out) {
  int wave = threadIdx.x >> 6, lane = threadIdx.x & 63;
  int t = blockIdx.x * 4 + wave;
  const float4* x4 = (const float4*)(hidden + (long long)t * 2048);
  float acc[16] = {};
  for (int c = lane; c < 512; c += 64) {
    float4 xv = x4[c];
#pragma unroll
    for (int h = 0; h < 16; ++h) {
      float4 wv = ((const float4*)(wp + h * 2048))[c];
      acc[h] += xv.x * wv.x + xv.y * wv.y + xv.z * wv.z + xv.w * wv.w;
    }
  }
#pragma unroll
  for (int h = 0; h < 16; ++h) {
    float s = wave_sum64(acc[h]);
    if (lane == 0) out[t * 16 + h] = s;
  }
}

// ================= indexer scores + exact fp32 top-256 (bitonic) =================
__global__ __launch_bounds__(256) void score_topk_k(
    const float* __restrict__ qi, const float* __restrict__ ki,
    const float* __restrict__ wproj, const int* __restrict__ ks,
    const int* __restrict__ ke, int* __restrict__ indices)
{
  int t = blockIdx.x, tid = threadIdx.x;
  __shared__ float s_qi[HI_ * DI_];
  __shared__ float s_w[HI_];
  __shared__ float s_score[T_];
  __shared__ int s_idx[T_];
  for (int i = tid; i < HI_ * DI_; i += 256) s_qi[i] = qi[(long long)t * HI_ * DI_ + i];
  if (tid < HI_) s_w[tid] = wproj[t * HI_ + tid] * 0.022097086912079608f;
  __syncthreads();
  int lo = ks[t], hi = ke[t];
  for (int s = tid; s < T_; s += 256) {
    const float4* kr = (const float4*)(ki + (long long)s * DI_);
    float dots[HI_] = {};
    for (int d4 = 0; d4 < DI_ / 4; ++d4) {
      float4 v = kr[d4];
      int d = d4 * 4;
#pragma unroll
      for (int h = 0; h < HI_; ++h) {
        const float* q = s_qi + h * DI_ + d;
        dots[h] += q[0] * v.x + q[1] * v.y + q[2] * v.z + q[3] * v.w;
      }
    }
    float sc = 0.f;
#pragma unroll
    for (int h = 0; h < HI_; ++h) sc += fmaxf(dots[h], 0.f) * s_w[h];
    bool valid = (s >= lo) && (s <= hi);
    s_score[s] = valid ? sc : NEGF;
    s_idx[s] = s;
  }
  __syncthreads();
  for (int k = 2; k <= T_; k <<= 1) {
    for (int j = k >> 1; j > 0; j >>= 1) {
      for (int i = tid; i < T_; i += 256) {
        int l = i ^ j;
        if (l > i) {
          float a = s_score[i], b = s_score[l];
          bool up = ((i & k) == 0);
          if (up ? (a > b) : (a < b)) {
            s_score[i] = b; s_score[l] = a;
            int ti = s_idx[i]; s_idx[i] = s_idx[l]; s_idx[l] = ti;
          }
        }
      }
      __syncthreads();
    }
  }
  if (tid < TOPK_) {
    float v = s_score[T_ - 1 - tid];
    int id = s_idx[T_ - 1 - tid];
    indices[t * TOPK_ + tid] = (v <= NEGF * 0.5f) ? T_ : id;
  }
}

// ================= gathered attention -> bf16 out =================
__global__ __launch_bounds__(256) void attn_k(
    const float* __restrict__ sq, const float* __restrict__ skv,
    const int* __restrict__ indices, __hip_bfloat16* __restrict__ attn_out)
{
  int t = blockIdx.x, tid = threadIdx.x;
  __shared__ float s_sq[H_ * 576];
  __shared__ float s_p[H_][TOPK_];
  __shared__ int s_ind[TOPK_];
  for (int i = tid; i < H_ * 576; i += 256) s_sq[i] = sq[(long long)t * H_ * 576 + i];
  s_ind[tid] = indices[t * TOPK_ + tid];
  __syncthreads();
  {
    int row = s_ind[tid];
    const float4* kv4 = (const float4*)(skv + (long long)row * 576);
    float acc[H_] = {};
    for (int d4 = 0; d4 < 144; ++d4) {
      float4 v = kv4[d4];
      int d = d4 * 4;
#pragma unroll
      for (int h = 0; h < H_; ++h) {
        const float* q = s_sq + h * 576 + d;
        acc[h] += q[0] * v.x + q[1] * v.y + q[2] * v.z + q[3] * v.w;
      }
    }
    const float scale = 0.07216878364870322f;
    bool masked = (row == T_);
#pragma unroll
    for (int h = 0; h < H_; ++h) s_p[h][tid] = masked ? NEGF : acc[h] * scale;
  }
  __syncthreads();
  int wave = tid >> 6, lane = tid & 63;
  for (int h = wave * 4; h < wave * 4 + 4; ++h) {
    float m = -3.4e38f;
    for (int j = lane; j < TOPK_; j += 64) m = fmaxf(m, s_p[h][j]);
#pragma unroll
    for (int off = 32; off; off >>= 1) m = fmaxf(m, __shfl_xor(m, off));
    float sum = 0.f;
    for (int j = lane; j < TOPK_; j += 64) {
      float e = __expf(s_p[h][j] - m);
      s_p[h][j] = e; sum += e;
    }
    sum = wave_sum64(sum);
    float inv = 1.f / sum;
    for (int j = lane; j < TOPK_; j += 64) s_p[h][j] *= inv;
  }
  __syncthreads();
  float a0[H_] = {}, a1[H_] = {};
  for (int j = 0; j < TOPK_; ++j) {
    const float* kv = skv + (long long)s_ind[j] * 576;
    float v0 = kv[tid], v1 = kv[tid + 256];
#pragma unroll
    for (int h = 0; h < H_; ++h) { float p = s_p[h][j]; a0[h] += p * v0; a1[h] += p * v1; }
  }
#pragma unroll
  for (int h = 0; h < H_; ++h) {
    attn_out[((long long)t * H_ + h) * 512 + tid] = __float2bfloat16(a0[h]);
    attn_out[((long long)t * H_ + h) * 512 + tid + 256] = __float2bfloat16(a1[h]);
  }
}

extern "C" void kernel_launch(void* const* d_in, const int* in_sizes, int n_in,
                              void* d_out, int out_size, void* d_ws, size_t ws_size,
                              hipStream_t stream) {
  const float* hidden  = (const float*)d_in[0];
  const float* cosb    = (const float*)d_in[1];
  const float* sinb    = (const float*)d_in[2];
  const int*   ks      = (const int*)d_in[3];
  const int*   ke      = (const int*)d_in[4];
  const float* w_qa    = (const float*)d_in[5];
  const float* g_qa    = (const float*)d_in[6];
  const float* w_qb    = (const float*)d_in[7];
  const float* w_kva   = (const float*)d_in[8];
  const float* g_kva   = (const float*)d_in[9];
  const float* w_kvb   = (const float*)d_in[10];
  const float* w_o     = (const float*)d_in[11];
  const float* i_wqb   = (const float*)d_in[12];
  const float* i_wk    = (const float*)d_in[13];
  const float* i_ln_w  = (const float*)d_in[14];
  const float* i_ln_b  = (const float*)d_in[15];
  const float* i_wproj = (const float*)d_in[16];
  float* out = (float*)d_out;
  (void)in_sizes; (void)n_in; (void)out_size; (void)ws_size;

  // ---- workspace (bytes), lifetime-overlapped; total 67,373,312 B ----
  char* ws = (char*)d_ws;
  __hip_bfloat16* hid_hi  = (__hip_bfloat16*)(ws + 0);          // 4 MB   [dead after ki gemm3]
  __hip_bfloat16* hid_lo  = (__hip_bfloat16*)(ws + 4194304);    // 4 MB   [dead after ki gemm3]
  float*          q_lat   = (float*)(ws + 8388608);             // 6 MB   [dead after decomp]
  __hip_bfloat16* qlat_hi = (__hip_bfloat16*)(ws + 14680064);   // 3 MB   [dead after q_full]
  __hip_bfloat16* qlat_lo = (__hip_bfloat16*)(ws + 17825792);   // 3 MB   [dead after qi gemm3]
  float*          qi      = (float*)(ws + 20971520);            // 8 MB   [dead after topk]
  float*          kib     = (float*)(ws + 29360128);            // 0.5 MB [dead after topk]
  float*          wbuf    = (float*)(ws + 29884416);            // 64 KB  [dead after topk]
  float*          ckv     = (float*)(ws + 29949952);            // 2.3 MB [dead after skv]
  float*          sqb     = (float*)(ws + 0);                   // 36 MB  [after all of region A dead]
  __hip_bfloat16* o_bf    = (__hip_bfloat16*)(ws + 0);          // 4 MB   [after sqb dead]
  __hip_bfloat16* W       = (__hip_bfloat16*)(ws + 37748736);   // 9.4 MB reused weight hi-buffer
  float*          skv     = (float*)(ws + 47185920);            // 2.36 MB
  int*            idxb    = (int*)(ws + 49547520);              // 1 MB
  __hip_bfloat16* E       = (__hip_bfloat16*)(ws + 50596096);   // 16.7 MB: Wlo / qfull_bf / attn_bf

  dim3 blk(256);
  const short* Ws = (const short*)W;
  const short* Es = (const short*)E;

  // hidden -> hi/lo
  decomp_k<<<2048, blk, 0, stream>>>(hidden, hid_hi, hid_lo, 524288);

  // q_lat = hidden @ w_qa.T  (bf16x3, fp32 out) ; RMS in fp32
  decomp_k<<<3072, blk, 0, stream>>>(w_qa, W, E, 786432);
  gemm3_k<<<dim3(12, 8), blk, 0, stream>>>(
      (const short*)hid_hi, (const short*)hid_lo, HID_, Ws, Es, HID_, q_lat, LQ_, LQ_, HID_);
  rms_inplace_k<<<T_, blk, 0, stream>>>(q_lat, g_qa, LQ_);

  // ckv = hidden @ w_kva.T (bf16 main path), skv build
  cast_pad_k<<<1280, blk, 0, stream>>>(w_kva, W, 576, 512, 640);
  gemm_bf_k<float><<<dim3(5, 8, 1), blk, 0, stream>>>(
      (const short*)hid_hi, HID_, 0, Ws, HID_, 0, ckv, 576, 0, 576, HID_);
  skv_build_k<<<T_ + 1, blk, 0, stream>>>(ckv, g_kva, cosb, sinb, skv);

  // q_lat -> hi/lo
  decomp_k<<<1536, blk, 0, stream>>>(q_lat, qlat_hi, qlat_lo, 393216);

  // qi = q_lat @ i_wqb.T (bf16x3, fp32 out), rope
  decomp_k<<<3072, blk, 0, stream>>>(i_wqb, W, E, 786432);
  gemm3_k<<<dim3(16, 8), blk, 0, stream>>>(
      (const short*)qlat_hi, (const short*)qlat_lo, LQ_, Ws, Es, LQ_, qi, HI_ * DI_, HI_ * DI_, LQ_);
  rope_qi_k<<<T_ * HI_, dim3(64), 0, stream>>>(qi, cosb, sinb);

  // ki = hidden @ i_wk.T (bf16x3, fp32 out), LN + rope
  decomp_k<<<256, blk, 0, stream>>>(i_wk, W, E, 65536);
  gemm3_k<<<dim3(1, 8), blk, 0, stream>>>(
      (const short*)hid_hi, (const short*)hid_lo, HID_, Ws, Es, HID_, kib, DI_, DI_, HID_);
  ki_ln_rope_k<<<T_, dim3(128), 0, stream>>>(kib, i_ln_w, i_ln_b, cosb, sinb);

  // w = hidden @ i_wproj.T (fp32)
  wproj_k<<<256, blk, 0, stream>>>(hidden, i_wproj, wbuf);

  // indexer top-256
  score_topk_k<<<T_, blk, 0, stream>>>(qi, kib, wbuf, ks, ke, idxb);

  // q_full = q_lat @ w_qb.T (bf16), rope tail -> sq
  cast_bf16_k<<<4608, blk, 0, stream>>>(w_qb, W, 1179648);
  gemm_bf_k<__hip_bfloat16><<<dim3(24, 8, 1), blk, 0, stream>>>(
      (const short*)qlat_hi, LQ_, 0, Ws, LQ_, 0, (__hip_bfloat16*)E, H_ * DQ_, 0, H_ * DQ_, LQ_);
  rope_q_sq_k<<<T_ * H_, dim3(64), 0, stream>>>(E, cosb, sinb, sqb);

  // q_abs = q_nope @ w_kn per head -> sq[...,0:512]
  wkn_t_k<<<4096, blk, 0, stream>>>(w_kvb, W);
  gemm_bf_k<float><<<dim3(4, 8, 16), blk, 0, stream>>>(
      Es, H_ * DQ_, 192, Ws, DI_, 65536, sqb, H_ * 576, 576, LKV_, DN_);

  // gathered attention -> bf16 (overwrites qfull region)
  attn_k<<<T_, blk, 0, stream>>>(sqb, skv, idxb, E);

  // o = attn @ w_v.T per head -> o_bf
  wv_cast_k<<<4096, blk, 0, stream>>>(w_kvb, W);
  gemm_bf_k<__hip_bfloat16><<<dim3(1, 8, 16), blk, 0, stream>>>(
      Es, H_ * LKV_, 512, Ws, LKV_, 65536, o_bf, H_ * DV_, 128, DV_, LKV_);

  // final = o @ w_o.T -> out (fp32)
  cast_bf16_k<<<4096, blk, 0, stream>>>(w_o, W, 1048576);
  gemm_bf_k<float><<<dim3(16, 8, 1), blk, 0, stream>>>(
      (const short*)o_bf, H_ * DV_, 0, Ws, H_ * DV_, 0, out, HID_, 0, HID_, H_ * DV_);
}

// Round 5
// 831.922 us; speedup vs baseline: 3.1091x; 1.1757x over previous
//
#include <hip/hip_runtime.h>
#include <hip/hip_bf16.h>
#include <cmath>

#define T_ 1024
#define HID_ 2048
#define H_ 16
#define LQ_ 1536
#define LKV_ 512
#define DR_ 64
#define DN_ 128
#define DQ_ 192
#define DV_ 128
#define HI_ 16
#define DI_ 128
#define TOPK_ 256
#define NEGF (-1e30f)

typedef short bfrag_t __attribute__((ext_vector_type(8)));   // 8 bf16 = 4 VGPRs
typedef float f32x4 __attribute__((ext_vector_type(4)));

__device__ __forceinline__ float wave_sum64(float v) {
#pragma unroll
  for (int off = 32; off; off >>= 1) v += __shfl_xor(v, off);
  return v;
}

// ================= bf16 MFMA GEMM: C = A @ B^T (verified R3/R4) =================
template<typename CT>
__global__ __launch_bounds__(256) void gemm_bf_k(
    const short* __restrict__ A, int lda, long long sA,
    const short* __restrict__ B, int ldb, long long sB,
    CT* __restrict__ C, int ldc, long long sC,
    int Nout, int K)
{
  __shared__ short As[128 * 32];
  __shared__ short Bs[128 * 32];
  A += (long long)blockIdx.z * sA;
  B += (long long)blockIdx.z * sB;
  C += (long long)blockIdx.z * sC;
  const int tid = threadIdx.x;
  const int bm = blockIdx.y * 128, bn = blockIdx.x * 128;
  const int wave = tid >> 6, lane = tid & 63;
  const int wm = (wave >> 1) * 64, wn = (wave & 1) * 64;
  const int sr = tid >> 2;
  const int scol = (tid & 3) * 8;
  const int m0 = lane & 15, koff = (lane >> 4) * 8;
  f32x4 acc[4][4] = {};
  const short* ga = A + (long long)(bm + sr) * lda + scol;
  const short* gb = B + (long long)(bn + sr) * ldb + scol;
  short* la = As + tid * 8;
  short* lb = Bs + tid * 8;
  for (int kk = 0; kk < K; kk += 32) {
    __builtin_amdgcn_global_load_lds((const __attribute__((address_space(1))) void*)(ga),
                                     (__attribute__((address_space(3))) void*)(la), 16, 0, 0);
    __builtin_amdgcn_global_load_lds((const __attribute__((address_space(1))) void*)(ga + 64 * lda),
                                     (__attribute__((address_space(3))) void*)(la + 2048), 16, 0, 0);
    __builtin_amdgcn_global_load_lds((const __attribute__((address_space(1))) void*)(gb),
                                     (__attribute__((address_space(3))) void*)(lb), 16, 0, 0);
    __builtin_amdgcn_global_load_lds((const __attribute__((address_space(1))) void*)(gb + 64 * ldb),
                                     (__attribute__((address_space(3))) void*)(lb + 2048), 16, 0, 0);
    ga += 32; gb += 32;
    __syncthreads();
    bfrag_t af[4], bfv[4];
#pragma unroll
    for (int i = 0; i < 4; ++i)
      af[i] = *(const bfrag_t*)(As + (wm + i * 16 + m0) * 32 + koff);
#pragma unroll
    for (int j = 0; j < 4; ++j)
      bfv[j] = *(const bfrag_t*)(Bs + (wn + j * 16 + m0) * 32 + koff);
#pragma unroll
    for (int i = 0; i < 4; ++i)
#pragma unroll
      for (int j = 0; j < 4; ++j)
        acc[i][j] = __builtin_amdgcn_mfma_f32_16x16x32_bf16(af[i], bfv[j], acc[i][j], 0, 0, 0);
    __syncthreads();
  }
  const int cr = (lane >> 4) * 4, cc = lane & 15;
#pragma unroll
  for (int i = 0; i < 4; ++i) {
    int row = bm + wm + i * 16 + cr;
#pragma unroll
    for (int j = 0; j < 4; ++j) {
      int col = bn + wn + j * 16 + cc;
      if (col < Nout) {
#pragma unroll
        for (int r = 0; r < 4; ++r)
          C[(long long)(row + r) * ldc + col] = (CT)(acc[i][j][r]);
      }
    }
  }
}

// ====== bf16x3 split GEMM (fp32-accurate, verified R4) ======
__global__ __launch_bounds__(256) void gemm3_k(
    const short* __restrict__ Ah, const short* __restrict__ Al, int lda,
    const short* __restrict__ Bh, const short* __restrict__ Bl, int ldb,
    float* __restrict__ C, int ldc, int Nout, int K)
{
  __shared__ short Ahs[128 * 32];
  __shared__ short Als[128 * 32];
  __shared__ short Bhs[128 * 32];
  __shared__ short Bls[128 * 32];
  const int tid = threadIdx.x;
  const int bm = blockIdx.y * 128, bn = blockIdx.x * 128;
  const int wave = tid >> 6, lane = tid & 63;
  const int wm = (wave >> 1) * 64, wn = (wave & 1) * 64;
  const int sr = tid >> 2;
  const int scol = (tid & 3) * 8;
  const int m0 = lane & 15, koff = (lane >> 4) * 8;
  f32x4 acc[4][4] = {};
  const short* gah = Ah + (long long)(bm + sr) * lda + scol;
  const short* gal = Al + (long long)(bm + sr) * lda + scol;
  const short* gbh = Bh + (long long)(bn + sr) * ldb + scol;
  const short* gbl = Bl + (long long)(bn + sr) * ldb + scol;
  short* lah = Ahs + tid * 8;
  short* lal = Als + tid * 8;
  short* lbh = Bhs + tid * 8;
  short* lbl = Bls + tid * 8;
  for (int kk = 0; kk < K; kk += 32) {
#define GLL(g, l) __builtin_amdgcn_global_load_lds((const __attribute__((address_space(1))) void*)(g), \
                                     (__attribute__((address_space(3))) void*)(l), 16, 0, 0)
    GLL(gah, lah); GLL(gah + 64 * lda, lah + 2048);
    GLL(gal, lal); GLL(gal + 64 * lda, lal + 2048);
    GLL(gbh, lbh); GLL(gbh + 64 * ldb, lbh + 2048);
    GLL(gbl, lbl); GLL(gbl + 64 * ldb, lbl + 2048);
#undef GLL
    gah += 32; gal += 32; gbh += 32; gbl += 32;
    __syncthreads();
    bfrag_t afh[4], afl[4], bfh[4], bfl[4];
#pragma unroll
    for (int i = 0; i < 4; ++i) {
      afh[i] = *(const bfrag_t*)(Ahs + (wm + i * 16 + m0) * 32 + koff);
      afl[i] = *(const bfrag_t*)(Als + (wm + i * 16 + m0) * 32 + koff);
    }
#pragma unroll
    for (int j = 0; j < 4; ++j) {
      bfh[j] = *(const bfrag_t*)(Bhs + (wn + j * 16 + m0) * 32 + koff);
      bfl[j] = *(const bfrag_t*)(Bls + (wn + j * 16 + m0) * 32 + koff);
    }
#pragma unroll
    for (int i = 0; i < 4; ++i)
#pragma unroll
      for (int j = 0; j < 4; ++j) {
        acc[i][j] = __builtin_amdgcn_mfma_f32_16x16x32_bf16(afh[i], bfh[j], acc[i][j], 0, 0, 0);
        acc[i][j] = __builtin_amdgcn_mfma_f32_16x16x32_bf16(afh[i], bfl[j], acc[i][j], 0, 0, 0);
        acc[i][j] = __builtin_amdgcn_mfma_f32_16x16x32_bf16(afl[i], bfh[j], acc[i][j], 0, 0, 0);
      }
    __syncthreads();
  }
  const int cr = (lane >> 4) * 4, cc = lane & 15;
#pragma unroll
  for (int i = 0; i < 4; ++i) {
    int row = bm + wm + i * 16 + cr;
#pragma unroll
    for (int j = 0; j < 4; ++j) {
      int col = bn + wn + j * 16 + cc;
      if (col < Nout) {
#pragma unroll
        for (int r = 0; r < 4; ++r)
          C[(long long)(row + r) * ldc + col] = acc[i][j][r];
      }
    }
  }
}

// ================= casts / decompose =================
__global__ __launch_bounds__(256) void cast_bf16_k(const float* __restrict__ src,
                                                   __hip_bfloat16* __restrict__ dst, int n4) {
  int i = blockIdx.x * 256 + threadIdx.x;
  if (i >= n4) return;
  float4 v = ((const float4*)src)[i];
  union { ushort4 u; __hip_bfloat16 h[4]; } o;
  o.h[0] = __float2bfloat16(v.x); o.h[1] = __float2bfloat16(v.y);
  o.h[2] = __float2bfloat16(v.z); o.h[3] = __float2bfloat16(v.w);
  ((ushort4*)dst)[i] = o.u;
}

__global__ __launch_bounds__(256) void decomp_k(const float* __restrict__ src,
                                                __hip_bfloat16* __restrict__ hi,
                                                __hip_bfloat16* __restrict__ lo, int n4) {
  int i = blockIdx.x * 256 + threadIdx.x;
  if (i >= n4) return;
  float4 v = ((const float4*)src)[i];
  float f[4] = {v.x, v.y, v.z, v.w};
  union { ushort4 u; __hip_bfloat16 h[4]; } oh, ol;
#pragma unroll
  for (int j = 0; j < 4; ++j) {
    __hip_bfloat16 h = __float2bfloat16(f[j]);
    oh.h[j] = h;
    ol.h[j] = __float2bfloat16(f[j] - __bfloat162float(h));
  }
  ((ushort4*)hi)[i] = oh.u;
  ((ushort4*)lo)[i] = ol.u;
}

__global__ __launch_bounds__(256) void cast_pad_k(const float* __restrict__ src,
                                                  __hip_bfloat16* __restrict__ dst,
                                                  int N, int K4, int Npad) {
  int i = blockIdx.x * 256 + threadIdx.x;
  if (i >= Npad * K4) return;
  int r = i / K4;
  float4 v = make_float4(0.f, 0.f, 0.f, 0.f);
  if (r < N) v = ((const float4*)src)[i];
  union { ushort4 u; __hip_bfloat16 h[4]; } o;
  o.h[0] = __float2bfloat16(v.x); o.h[1] = __float2bfloat16(v.y);
  o.h[2] = __float2bfloat16(v.z); o.h[3] = __float2bfloat16(v.w);
  ((ushort4*)dst)[i] = o.u;
}

__global__ __launch_bounds__(256) void wkn_t_k(const float* __restrict__ wkvb,
                                               __hip_bfloat16* __restrict__ dst) {
  int i = blockIdx.x * 256 + threadIdx.x;
  int d = i & 127, k = (i >> 7) & 511, h = i >> 16;
  dst[i] = __float2bfloat16(wkvb[((h * 256 + d) << 9) + k]);
}

__global__ __launch_bounds__(256) void wv_cast_k(const float* __restrict__ wkvb,
                                                 __hip_bfloat16* __restrict__ dst) {
  int i = blockIdx.x * 256 + threadIdx.x;
  int k = i & 511, dv = (i >> 9) & 127, h = i >> 16;
  dst[i] = __float2bfloat16(wkvb[((h * 256 + 128 + dv) << 9) + k]);
}

// ================= RMSNorm in-place (fp32) =================
__global__ __launch_bounds__(256) void rms_inplace_k(float* x, const float* __restrict__ g,
                                                     int C) {
  int t = blockIdx.x, tid = threadIdx.x;
  float* row = x + (long long)t * C;
  float ss = 0.f;
  for (int i = tid; i < C; i += 256) { float v = row[i]; ss += v * v; }
  __shared__ float red[4];
  ss = wave_sum64(ss);
  if ((tid & 63) == 0) red[tid >> 6] = ss;
  __syncthreads();
  float sc = rsqrtf((red[0] + red[1] + red[2] + red[3]) / (float)C + 1e-6f);
  for (int i = tid; i < C; i += 256) row[i] = row[i] * sc * g[i];
}

// ================= skv build -> bf16; row T_ = 0 =================
__global__ __launch_bounds__(256) void skv_build_k(const float* __restrict__ ckv,
                                                   const float* __restrict__ g,
                                                   const float* __restrict__ cosb,
                                                   const float* __restrict__ sinb,
                                                   __hip_bfloat16* __restrict__ skv) {
  int t = blockIdx.x, tid = threadIdx.x;
  __hip_bfloat16* out = skv + (long long)t * 576;
  if (t == T_) { for (int i = tid; i < 576; i += 256) out[i] = __float2bfloat16(0.f); return; }
  const float* row = ckv + (long long)t * 576;
  float ss = 0.f;
  for (int i = tid; i < 512; i += 256) { float v = row[i]; ss += v * v; }
  __shared__ float red[4];
  ss = wave_sum64(ss);
  if ((tid & 63) == 0) red[tid >> 6] = ss;
  __syncthreads();
  float sc = rsqrtf((red[0] + red[1] + red[2] + red[3]) / 512.f + 1e-6f);
  for (int i = tid; i < 512; i += 256) out[i] = __float2bfloat16(row[i] * sc * g[i]);
  if (tid < 64) {
    int j = tid, j2 = tid & 31;
    float c = cosb[t * 64 + j], s = sinb[t * 64 + j];
    float a = row[512 + 2 * j2], b = row[512 + 2 * j2 + 1];
    out[512 + j] = __float2bfloat16((j < 32) ? (a * c - b * s) : (a * s + b * c));
  }
}

// ================= rope in-place on qi heads (fp32) =================
__global__ __launch_bounds__(64) void rope_qi_k(float* qi, const float* __restrict__ cosb,
                                                const float* __restrict__ sinb) {
  int b = blockIdx.x, t = b >> 4, j = threadIdx.x, j2 = j & 31;
  float* x = qi + (long long)b * DI_;
  float c = cosb[t * 64 + j], s = sinb[t * 64 + j];
  float a = x[2 * j2], bb = x[2 * j2 + 1];
  float o = (j < 32) ? (a * c - bb * s) : (a * s + bb * c);
  x[j] = o;
}

// ================= ki: LayerNorm then rope, in-place (fp32) =================
__global__ __launch_bounds__(128) void ki_ln_rope_k(float* kbuf, const float* __restrict__ w,
                                                    const float* __restrict__ bia,
                                                    const float* __restrict__ cosb,
                                                    const float* __restrict__ sinb) {
  int t = blockIdx.x, i = threadIdx.x;
  float* row = kbuf + (long long)t * DI_;
  float x = row[i];
  __shared__ float red[2];
  float s1 = wave_sum64(x);
  if ((i & 63) == 0) red[i >> 6] = s1;
  __syncthreads();
  float mean = (red[0] + red[1]) / 128.f;
  float d = x - mean;
  __syncthreads();
  float s2 = wave_sum64(d * d);
  if ((i & 63) == 0) red[i >> 6] = s2;
  __syncthreads();
  float var = (red[0] + red[1]) / 128.f;
  float y = d * rsqrtf(var + 1e-6f) * w[i] + bia[i];
  __shared__ float rowl[128];
  rowl[i] = y;
  __syncthreads();
  float outv = y;
  if (i < 64) {
    int j2 = i & 31;
    float c = cosb[t * 64 + i], s = sinb[t * 64 + i];
    float a = rowl[2 * j2], b = rowl[2 * j2 + 1];
    outv = (i < 32) ? (a * c - b * s) : (a * s + b * c);
  }
  row[i] = outv;
}

// ================= rope q_full tail (bf16 in) -> sq_bf[...,512:576] =================
__global__ __launch_bounds__(64) void rope_q_sq_k(const __hip_bfloat16* __restrict__ qfull,
                                                  const float* __restrict__ cosb,
                                                  const float* __restrict__ sinb,
                                                  __hip_bfloat16* __restrict__ sq) {
  int b = blockIdx.x, t = b >> 4, h = b & 15, j = threadIdx.x, j2 = j & 31;
  const __hip_bfloat16* x = qfull + (long long)t * 3072 + h * 192 + 128;
  float c = cosb[t * 64 + j], s = sinb[t * 64 + j];
  float a = __bfloat162float(x[2 * j2]), bb = __bfloat162float(x[2 * j2 + 1]);
  float o = (j < 32) ? (a * c - bb * s) : (a * s + bb * c);
  sq[((long long)t * H_ + h) * 576 + 512 + j] = __float2bfloat16(o);
}

// ================= w = hidden @ i_wproj.T (fp32) =================
__global__ __launch_bounds__(256) void wproj_k(const float* __restrict__ hidden,
                                               const float* __restrict__ wp,
                                               float* __restrict__ out) {
  int wave = threadIdx.x >> 6, lane = threadIdx.x & 63;
  int t = blockIdx.x * 4 + wave;
  const float4* x4 = (const float4*)(hidden + (long long)t * 2048);
  float acc[16] = {};
  for (int c = lane; c < 512; c += 64) {
    float4 xv = x4[c];
#pragma unroll
    for (int h = 0; h < 16; ++h) {
      float4 wv = ((const float4*)(wp + h * 2048))[c];
      acc[h] += xv.x * wv.x + xv.y * wv.y + xv.z * wv.z + xv.w * wv.w;
    }
  }
#pragma unroll
  for (int h = 0; h < 16; ++h) {
    float s = wave_sum64(acc[h]);
    if (lane == 0) out[t * 16 + h] = s;
  }
}

// ================= indexer scores + exact fp32 top-256 (bitonic) =================
__global__ __launch_bounds__(256) void score_topk_k(
    const float* __restrict__ qi, const float* __restrict__ ki,
    const float* __restrict__ wproj, const int* __restrict__ ks,
    const int* __restrict__ ke, int* __restrict__ indices)
{
  int t = blockIdx.x, tid = threadIdx.x;
  __shared__ float s_qi[HI_ * DI_];
  __shared__ float s_w[HI_];
  __shared__ float s_score[T_];
  __shared__ int s_idx[T_];
  for (int i = tid; i < HI_ * DI_; i += 256) s_qi[i] = qi[(long long)t * HI_ * DI_ + i];
  if (tid < HI_) s_w[tid] = wproj[t * HI_ + tid] * 0.022097086912079608f;
  __syncthreads();
  int lo = ks[t], hi = ke[t];
  for (int s = tid; s < T_; s += 256) {
    const float4* kr = (const float4*)(ki + (long long)s * DI_);
    float dots[HI_] = {};
    for (int d4 = 0; d4 < DI_ / 4; ++d4) {
      float4 v = kr[d4];
      int d = d4 * 4;
#pragma unroll
      for (int h = 0; h < HI_; ++h) {
        const float* q = s_qi + h * DI_ + d;
        dots[h] += q[0] * v.x + q[1] * v.y + q[2] * v.z + q[3] * v.w;
      }
    }
    float sc = 0.f;
#pragma unroll
    for (int h = 0; h < HI_; ++h) sc += fmaxf(dots[h], 0.f) * s_w[h];
    bool valid = (s >= lo) && (s <= hi);
    s_score[s] = valid ? sc : NEGF;
    s_idx[s] = s;
  }
  __syncthreads();
  for (int k = 2; k <= T_; k <<= 1) {
    for (int j = k >> 1; j > 0; j >>= 1) {
      for (int i = tid; i < T_; i += 256) {
        int l = i ^ j;
        if (l > i) {
          float a = s_score[i], b = s_score[l];
          bool up = ((i & k) == 0);
          if (up ? (a > b) : (a < b)) {
            s_score[i] = b; s_score[l] = a;
            int ti = s_idx[i]; s_idx[i] = s_idx[l]; s_idx[l] = ti;
          }
        }
      }
      __syncthreads();
    }
  }
  if (tid < TOPK_) {
    float v = s_score[T_ - 1 - tid];
    int id = s_idx[T_ - 1 - tid];
    indices[t * TOPK_ + tid] = (v <= NEGF * 0.5f) ? T_ : id;
  }
}

// ================= MFMA gathered attention =================
// One block per query t. QK^T: A/B frags direct from global (L2-hot).
// PV: P->bf16 A-layout in LDS; V per-64-col chunk transposed in LDS.
#define SP_LD 257   // fp32 stride (head -> bank spread)
#define PB_LD 264   // bf16 stride, 16B-aligned
__global__ __launch_bounds__(256) void attn_k(
    const short* __restrict__ sq, const short* __restrict__ skv,
    const int* __restrict__ indices, __hip_bfloat16* __restrict__ attn_out)
{
  __shared__ int s_ind[TOPK_];
  __shared__ float s_p[H_ * SP_LD];
  __shared__ short s_pb[H_ * PB_LD];
  __shared__ short s_vt[64 * PB_LD];
  const int t = blockIdx.x, tid = threadIdx.x;
  const int wave = tid >> 6, lane = tid & 63;
  const int m0 = lane & 15, quad = lane >> 4;
  s_ind[tid] = indices[t * TOPK_ + tid];
  __syncthreads();

  // ---- phase 1: logits = sq @ kv^T (per wave: 64 keys) ----
  {
    const int jb = wave * 64;
    int rows[4];
    const short* kvp[4];
#pragma unroll
    for (int j = 0; j < 4; ++j) {
      rows[j] = s_ind[jb + j * 16 + m0];
      kvp[j] = skv + rows[j] * 576 + quad * 8;
    }
    const short* qp = sq + ((long long)t * H_ + m0) * 576 + quad * 8;
    f32x4 qacc[4] = {};
    for (int ks = 0; ks < 18; ++ks) {
      const int k0 = ks * 32;
      bfrag_t aq = *(const bfrag_t*)(qp + k0);
#pragma unroll
      for (int j = 0; j < 4; ++j) {
        bfrag_t bq = *(const bfrag_t*)(kvp[j] + k0);
        qacc[j] = __builtin_amdgcn_mfma_f32_16x16x32_bf16(aq, bq, qacc[j], 0, 0, 0);
      }
    }
    const float scale = 0.07216878364870322f; // 192^-0.5
#pragma unroll
    for (int j = 0; j < 4; ++j) {
      int key = jb + j * 16 + m0;
      bool msk = (rows[j] == T_);
#pragma unroll
      for (int r = 0; r < 4; ++r)
        s_p[(quad * 4 + r) * SP_LD + key] = msk ? NEGF : qacc[j][r] * scale;
    }
  }
  __syncthreads();

  // ---- phase 2: softmax (wave w handles heads 4w..4w+3) ----
  for (int h = wave * 4; h < wave * 4 + 4; ++h) {
    float* ph = s_p + h * SP_LD;
    float m = -3.4e38f;
    for (int j = lane; j < TOPK_; j += 64) m = fmaxf(m, ph[j]);
#pragma unroll
    for (int off = 32; off; off >>= 1) m = fmaxf(m, __shfl_xor(m, off));
    float sum = 0.f;
    for (int j = lane; j < TOPK_; j += 64) {
      float e = __expf(ph[j] - m);
      ph[j] = e; sum += e;
    }
    sum = wave_sum64(sum);
    float inv = 1.f / sum;
    for (int j = lane; j < TOPK_; j += 64) ph[j] *= inv;
  }
  __syncthreads();

  // ---- P -> bf16 A-layout ----
#pragma unroll
  for (int h = 0; h < H_; ++h)
    s_pb[h * PB_LD + tid] = (short)__bfloat16_as_ushort(__float2bfloat16(s_p[h * SP_LD + tid]));
  __syncthreads();

  // A-frags for PV live in registers across all chunks
  bfrag_t apf[8];
#pragma unroll
  for (int kk = 0; kk < 8; ++kk)
    apf[kk] = *(const bfrag_t*)(s_pb + m0 * PB_LD + kk * 32 + quad * 8);

  const int myrow = s_ind[tid];
  const short* vsrc = skv + myrow * 576;

  // ---- phase 3: PV, 8 chunks of 64 cols ----
  for (int c = 0; c < 8; ++c) {
    const int c0 = c * 64;
    // stage transposed V chunk: s_vt[col_local][key]
#pragma unroll
    for (int b = 0; b < 8; ++b) {
      bfrag_t v = *(const bfrag_t*)(vsrc + c0 + b * 8);
#pragma unroll
      for (int j = 0; j < 8; ++j)
        s_vt[(b * 8 + j) * PB_LD + tid] = v[j];
    }
    __syncthreads();
    // each wave: 16 cols of this chunk
    const short* vb = s_vt + (wave * 16 + m0) * PB_LD + quad * 8;
    f32x4 oacc = {0.f, 0.f, 0.f, 0.f};
#pragma unroll
    for (int kk = 0; kk < 8; ++kk) {
      bfrag_t bv = *(const bfrag_t*)(vb + kk * 32);
      oacc = __builtin_amdgcn_mfma_f32_16x16x32_bf16(apf[kk], bv, oacc, 0, 0, 0);
    }
    const int col = c0 + wave * 16 + m0;
#pragma unroll
    for (int r = 0; r < 4; ++r)
      attn_out[((long long)t * H_ + quad * 4 + r) * 512 + col] = __float2bfloat16(oacc[r]);
    __syncthreads();
  }
}

extern "C" void kernel_launch(void* const* d_in, const int* in_sizes, int n_in,
                              void* d_out, int out_size, void* d_ws, size_t ws_size,
                              hipStream_t stream) {
  const float* hidden  = (const float*)d_in[0];
  const float* cosb    = (const float*)d_in[1];
  const float* sinb    = (const float*)d_in[2];
  const int*   ks      = (const int*)d_in[3];
  const int*   ke      = (const int*)d_in[4];
  const float* w_qa    = (const float*)d_in[5];
  const float* g_qa    = (const float*)d_in[6];
  const float* w_qb    = (const float*)d_in[7];
  const float* w_kva   = (const float*)d_in[8];
  const float* g_kva   = (const float*)d_in[9];
  const float* w_kvb   = (const float*)d_in[10];
  const float* w_o     = (const float*)d_in[11];
  const float* i_wqb   = (const float*)d_in[12];
  const float* i_wk    = (const float*)d_in[13];
  const float* i_ln_w  = (const float*)d_in[14];
  const float* i_ln_b  = (const float*)d_in[15];
  const float* i_wproj = (const float*)d_in[16];
  float* out = (float*)d_out;
  (void)in_sizes; (void)n_in; (void)out_size; (void)ws_size;

  // ---- workspace (bytes), lifetime-overlapped; total 66.2 MB ----
  char* ws = (char*)d_ws;
  __hip_bfloat16* hid_hi  = (__hip_bfloat16*)(ws + 0);          // 4 MB   [dead after ki gemm3]
  __hip_bfloat16* hid_lo  = (__hip_bfloat16*)(ws + 4194304);    // 4 MB
  float*          q_lat   = (float*)(ws + 8388608);             // 6 MB
  __hip_bfloat16* qlat_hi = (__hip_bfloat16*)(ws + 14680064);   // 3 MB   [dead after q_full]
  __hip_bfloat16* qlat_lo = (__hip_bfloat16*)(ws + 17825792);   // 3 MB
  float*          qi      = (float*)(ws + 20971520);            // 8 MB   [dead after topk]
  float*          kib     = (float*)(ws + 29360128);            // 0.5 MB
  float*          wbuf    = (float*)(ws + 29884416);            // 64 KB
  float*          ckv     = (float*)(ws + 29949952);            // 2.3 MB [dead after skv]
  __hip_bfloat16* sq_bf   = (__hip_bfloat16*)(ws + 0);          // 18.9 MB [after region A dead]
  __hip_bfloat16* o_bf    = (__hip_bfloat16*)(ws + 0);          // 4 MB   [after sq_bf dead]
  __hip_bfloat16* W       = (__hip_bfloat16*)(ws + 37748736);   // 9.4 MB weight hi-buffer
  __hip_bfloat16* skv_bf  = (__hip_bfloat16*)(ws + 47185920);   // 1.18 MB
  int*            idxb    = (int*)(ws + 48366720);              // 1 MB
  __hip_bfloat16* E       = (__hip_bfloat16*)(ws + 49415296);   // 16.7 MB: Wlo / qfull / attn_bf

  dim3 blk(256);
  const short* Ws = (const short*)W;
  const short* Es = (const short*)E;

  // hidden -> hi/lo
  decomp_k<<<2048, blk, 0, stream>>>(hidden, hid_hi, hid_lo, 524288);

  // q_lat = hidden @ w_qa.T (bf16x3); RMS fp32
  decomp_k<<<3072, blk, 0, stream>>>(w_qa, W, E, 786432);
  gemm3_k<<<dim3(12, 8), blk, 0, stream>>>(
      (const short*)hid_hi, (const short*)hid_lo, HID_, Ws, Es, HID_, q_lat, LQ_, LQ_, HID_);
  rms_inplace_k<<<T_, blk, 0, stream>>>(q_lat, g_qa, LQ_);

  // ckv = hidden @ w_kva.T (bf16), skv build -> bf16
  cast_pad_k<<<1280, blk, 0, stream>>>(w_kva, W, 576, 512, 640);
  gemm_bf_k<float><<<dim3(5, 8, 1), blk, 0, stream>>>(
      (const short*)hid_hi, HID_, 0, Ws, HID_, 0, ckv, 576, 0, 576, HID_);
  skv_build_k<<<T_ + 1, blk, 0, stream>>>(ckv, g_kva, cosb, sinb, skv_bf);

  // q_lat -> hi/lo
  decomp_k<<<1536, blk, 0, stream>>>(q_lat, qlat_hi, qlat_lo, 393216);

  // qi = q_lat @ i_wqb.T (bf16x3), rope
  decomp_k<<<3072, blk, 0, stream>>>(i_wqb, W, E, 786432);
  gemm3_k<<<dim3(16, 8), blk, 0, stream>>>(
      (const short*)qlat_hi, (const short*)qlat_lo, LQ_, Ws, Es, LQ_, qi, HI_ * DI_, HI_ * DI_, LQ_);
  rope_qi_k<<<T_ * HI_, dim3(64), 0, stream>>>(qi, cosb, sinb);

  // ki = hidden @ i_wk.T (bf16x3), LN + rope
  decomp_k<<<256, blk, 0, stream>>>(i_wk, W, E, 65536);
  gemm3_k<<<dim3(1, 8), blk, 0, stream>>>(
      (const short*)hid_hi, (const short*)hid_lo, HID_, Ws, Es, HID_, kib, DI_, DI_, HID_);
  ki_ln_rope_k<<<T_, dim3(128), 0, stream>>>(kib, i_ln_w, i_ln_b, cosb, sinb);

  // w = hidden @ i_wproj.T (fp32)
  wproj_k<<<256, blk, 0, stream>>>(hidden, i_wproj, wbuf);

  // indexer top-256
  score_topk_k<<<T_, blk, 0, stream>>>(qi, kib, wbuf, ks, ke, idxb);

  // q_full = q_lat @ w_qb.T (bf16 -> E), rope tail -> sq_bf
  cast_bf16_k<<<4608, blk, 0, stream>>>(w_qb, W, 1179648);
  gemm_bf_k<__hip_bfloat16><<<dim3(24, 8, 1), blk, 0, stream>>>(
      (const short*)qlat_hi, LQ_, 0, Ws, LQ_, 0, (__hip_bfloat16*)E, H_ * DQ_, 0, H_ * DQ_, LQ_);
  rope_q_sq_k<<<T_ * H_, dim3(64), 0, stream>>>(E, cosb, sinb, sq_bf);

  // q_abs = q_nope @ w_kn per head -> sq_bf[...,0:512] (bf16)
  wkn_t_k<<<4096, blk, 0, stream>>>(w_kvb, W);
  gemm_bf_k<__hip_bfloat16><<<dim3(4, 8, 16), blk, 0, stream>>>(
      Es, H_ * DQ_, 192, Ws, DI_, 65536, sq_bf, H_ * 576, 576, LKV_, DN_);

  // MFMA gathered attention -> E (bf16)
  attn_k<<<T_, blk, 0, stream>>>((const short*)sq_bf, (const short*)skv_bf, idxb, E);

  // o = attn @ w_v.T per head -> o_bf
  wv_cast_k<<<4096, blk, 0, stream>>>(w_kvb, W);
  gemm_bf_k<__hip_bfloat16><<<dim3(1, 8, 16), blk, 0, stream>>>(
      Es, H_ * LKV_, 512, Ws, LKV_, 65536, o_bf, H_ * DV_, 128, DV_, LKV_);

  // final = o @ w_o.T -> out (fp32)
  cast_bf16_k<<<4096, blk, 0, stream>>>(w_o, W, 1048576);
  gemm_bf_k<float><<<dim3(16, 8, 1), blk, 0, stream>>>(
      (const short*)o_bf, H_ * DV_, 0, Ws, H_ * DV_, 0, out, HID_, 0, HID_, H_ * DV_);
}

// Round 6
// 743.885 us; speedup vs baseline: 3.4770x; 1.1183x over previous
//
#include <hip/hip_runtime.h>
#include <hip/hip_bf16.h>
#include <cmath>

#define T_ 1024
#define HID_ 2048
#define H_ 16
#define LQ_ 1536
#define LKV_ 512
#define DR_ 64
#define DN_ 128
#define DQ_ 192
#define DV_ 128
#define HI_ 16
#define DI_ 128
#define TOPK_ 256
#define NEGF (-1e30f)

typedef short bfrag_t __attribute__((ext_vector_type(8)));   // 8 bf16 = 4 VGPRs
typedef float f32x4 __attribute__((ext_vector_type(4)));

__device__ __forceinline__ float wave_sum64(float v) {
#pragma unroll
  for (int off = 32; off; off >>= 1) v += __shfl_xor(v, off);
  return v;
}

// ================= bf16 MFMA GEMM: C = A @ B^T (verified R3/R4) =================
template<typename CT>
__global__ __launch_bounds__(256) void gemm_bf_k(
    const short* __restrict__ A, int lda, long long sA,
    const short* __restrict__ B, int ldb, long long sB,
    CT* __restrict__ C, int ldc, long long sC,
    int Nout, int K)
{
  __shared__ short As[128 * 32];
  __shared__ short Bs[128 * 32];
  A += (long long)blockIdx.z * sA;
  B += (long long)blockIdx.z * sB;
  C += (long long)blockIdx.z * sC;
  const int tid = threadIdx.x;
  const int bm = blockIdx.y * 128, bn = blockIdx.x * 128;
  const int wave = tid >> 6, lane = tid & 63;
  const int wm = (wave >> 1) * 64, wn = (wave & 1) * 64;
  const int sr = tid >> 2;
  const int scol = (tid & 3) * 8;
  const int m0 = lane & 15, koff = (lane >> 4) * 8;
  f32x4 acc[4][4] = {};
  const short* ga = A + (long long)(bm + sr) * lda + scol;
  const short* gb = B + (long long)(bn + sr) * ldb + scol;
  short* la = As + tid * 8;
  short* lb = Bs + tid * 8;
  for (int kk = 0; kk < K; kk += 32) {
    __builtin_amdgcn_global_load_lds((const __attribute__((address_space(1))) void*)(ga),
                                     (__attribute__((address_space(3))) void*)(la), 16, 0, 0);
    __builtin_amdgcn_global_load_lds((const __attribute__((address_space(1))) void*)(ga + 64 * lda),
                                     (__attribute__((address_space(3))) void*)(la + 2048), 16, 0, 0);
    __builtin_amdgcn_global_load_lds((const __attribute__((address_space(1))) void*)(gb),
                                     (__attribute__((address_space(3))) void*)(lb), 16, 0, 0);
    __builtin_amdgcn_global_load_lds((const __attribute__((address_space(1))) void*)(gb + 64 * ldb),
                                     (__attribute__((address_space(3))) void*)(lb + 2048), 16, 0, 0);
    ga += 32; gb += 32;
    __syncthreads();
    bfrag_t af[4], bfv[4];
#pragma unroll
    for (int i = 0; i < 4; ++i)
      af[i] = *(const bfrag_t*)(As + (wm + i * 16 + m0) * 32 + koff);
#pragma unroll
    for (int j = 0; j < 4; ++j)
      bfv[j] = *(const bfrag_t*)(Bs + (wn + j * 16 + m0) * 32 + koff);
#pragma unroll
    for (int i = 0; i < 4; ++i)
#pragma unroll
      for (int j = 0; j < 4; ++j)
        acc[i][j] = __builtin_amdgcn_mfma_f32_16x16x32_bf16(af[i], bfv[j], acc[i][j], 0, 0, 0);
    __syncthreads();
  }
  const int cr = (lane >> 4) * 4, cc = lane & 15;
#pragma unroll
  for (int i = 0; i < 4; ++i) {
    int row = bm + wm + i * 16 + cr;
#pragma unroll
    for (int j = 0; j < 4; ++j) {
      int col = bn + wn + j * 16 + cc;
      if (col < Nout) {
#pragma unroll
        for (int r = 0; r < 4; ++r)
          C[(long long)(row + r) * ldc + col] = (CT)(acc[i][j][r]);
      }
    }
  }
}

// ====== bf16x3 split GEMM (fp32-accurate, verified R4) ======
__global__ __launch_bounds__(256) void gemm3_k(
    const short* __restrict__ Ah, const short* __restrict__ Al, int lda,
    const short* __restrict__ Bh, const short* __restrict__ Bl, int ldb,
    float* __restrict__ C, int ldc, int Nout, int K)
{
  __shared__ short Ahs[128 * 32];
  __shared__ short Als[128 * 32];
  __shared__ short Bhs[128 * 32];
  __shared__ short Bls[128 * 32];
  const int tid = threadIdx.x;
  const int bm = blockIdx.y * 128, bn = blockIdx.x * 128;
  const int wave = tid >> 6, lane = tid & 63;
  const int wm = (wave >> 1) * 64, wn = (wave & 1) * 64;
  const int sr = tid >> 2;
  const int scol = (tid & 3) * 8;
  const int m0 = lane & 15, koff = (lane >> 4) * 8;
  f32x4 acc[4][4] = {};
  const short* gah = Ah + (long long)(bm + sr) * lda + scol;
  const short* gal = Al + (long long)(bm + sr) * lda + scol;
  const short* gbh = Bh + (long long)(bn + sr) * ldb + scol;
  const short* gbl = Bl + (long long)(bn + sr) * ldb + scol;
  short* lah = Ahs + tid * 8;
  short* lal = Als + tid * 8;
  short* lbh = Bhs + tid * 8;
  short* lbl = Bls + tid * 8;
  for (int kk = 0; kk < K; kk += 32) {
#define GLL(g, l) __builtin_amdgcn_global_load_lds((const __attribute__((address_space(1))) void*)(g), \
                                     (__attribute__((address_space(3))) void*)(l), 16, 0, 0)
    GLL(gah, lah); GLL(gah + 64 * lda, lah + 2048);
    GLL(gal, lal); GLL(gal + 64 * lda, lal + 2048);
    GLL(gbh, lbh); GLL(gbh + 64 * ldb, lbh + 2048);
    GLL(gbl, lbl); GLL(gbl + 64 * ldb, lbl + 2048);
#undef GLL
    gah += 32; gal += 32; gbh += 32; gbl += 32;
    __syncthreads();
    bfrag_t afh[4], afl[4], bfh[4], bfl[4];
#pragma unroll
    for (int i = 0; i < 4; ++i) {
      afh[i] = *(const bfrag_t*)(Ahs + (wm + i * 16 + m0) * 32 + koff);
      afl[i] = *(const bfrag_t*)(Als + (wm + i * 16 + m0) * 32 + koff);
    }
#pragma unroll
    for (int j = 0; j < 4; ++j) {
      bfh[j] = *(const bfrag_t*)(Bhs + (wn + j * 16 + m0) * 32 + koff);
      bfl[j] = *(const bfrag_t*)(Bls + (wn + j * 16 + m0) * 32 + koff);
    }
#pragma unroll
    for (int i = 0; i < 4; ++i)
#pragma unroll
      for (int j = 0; j < 4; ++j) {
        acc[i][j] = __builtin_amdgcn_mfma_f32_16x16x32_bf16(afh[i], bfh[j], acc[i][j], 0, 0, 0);
        acc[i][j] = __builtin_amdgcn_mfma_f32_16x16x32_bf16(afh[i], bfl[j], acc[i][j], 0, 0, 0);
        acc[i][j] = __builtin_amdgcn_mfma_f32_16x16x32_bf16(afl[i], bfh[j], acc[i][j], 0, 0, 0);
      }
    __syncthreads();
  }
  const int cr = (lane >> 4) * 4, cc = lane & 15;
#pragma unroll
  for (int i = 0; i < 4; ++i) {
    int row = bm + wm + i * 16 + cr;
#pragma unroll
    for (int j = 0; j < 4; ++j) {
      int col = bn + wn + j * 16 + cc;
      if (col < Nout) {
#pragma unroll
        for (int r = 0; r < 4; ++r)
          C[(long long)(row + r) * ldc + col] = acc[i][j][r];
      }
    }
  }
}

// ================= casts / decompose =================
__global__ __launch_bounds__(256) void cast_bf16_k(const float* __restrict__ src,
                                                   __hip_bfloat16* __restrict__ dst, int n4) {
  int i = blockIdx.x * 256 + threadIdx.x;
  if (i >= n4) return;
  float4 v = ((const float4*)src)[i];
  union { ushort4 u; __hip_bfloat16 h[4]; } o;
  o.h[0] = __float2bfloat16(v.x); o.h[1] = __float2bfloat16(v.y);
  o.h[2] = __float2bfloat16(v.z); o.h[3] = __float2bfloat16(v.w);
  ((ushort4*)dst)[i] = o.u;
}

__global__ __launch_bounds__(256) void decomp_k(const float* __restrict__ src,
                                                __hip_bfloat16* __restrict__ hi,
                                                __hip_bfloat16* __restrict__ lo, int n4) {
  int i = blockIdx.x * 256 + threadIdx.x;
  if (i >= n4) return;
  float4 v = ((const float4*)src)[i];
  float f[4] = {v.x, v.y, v.z, v.w};
  union { ushort4 u; __hip_bfloat16 h[4]; } oh, ol;
#pragma unroll
  for (int j = 0; j < 4; ++j) {
    __hip_bfloat16 h = __float2bfloat16(f[j]);
    oh.h[j] = h;
    ol.h[j] = __float2bfloat16(f[j] - __bfloat162float(h));
  }
  ((ushort4*)hi)[i] = oh.u;
  ((ushort4*)lo)[i] = ol.u;
}

__global__ __launch_bounds__(256) void cast_pad_k(const float* __restrict__ src,
                                                  __hip_bfloat16* __restrict__ dst,
                                                  int N, int K4, int Npad) {
  int i = blockIdx.x * 256 + threadIdx.x;
  if (i >= Npad * K4) return;
  int r = i / K4;
  float4 v = make_float4(0.f, 0.f, 0.f, 0.f);
  if (r < N) v = ((const float4*)src)[i];
  union { ushort4 u; __hip_bfloat16 h[4]; } o;
  o.h[0] = __float2bfloat16(v.x); o.h[1] = __float2bfloat16(v.y);
  o.h[2] = __float2bfloat16(v.z); o.h[3] = __float2bfloat16(v.w);
  ((ushort4*)dst)[i] = o.u;
}

__global__ __launch_bounds__(256) void wkn_t_k(const float* __restrict__ wkvb,
                                               __hip_bfloat16* __restrict__ dst) {
  int i = blockIdx.x * 256 + threadIdx.x;
  int d = i & 127, k = (i >> 7) & 511, h = i >> 16;
  dst[i] = __float2bfloat16(wkvb[((h * 256 + d) << 9) + k]);
}

__global__ __launch_bounds__(256) void wv_cast_k(const float* __restrict__ wkvb,
                                                 __hip_bfloat16* __restrict__ dst) {
  int i = blockIdx.x * 256 + threadIdx.x;
  int k = i & 511, dv = (i >> 9) & 127, h = i >> 16;
  dst[i] = __float2bfloat16(wkvb[((h * 256 + 128 + dv) << 9) + k]);
}

// ================= RMSNorm in-place (fp32) =================
__global__ __launch_bounds__(256) void rms_inplace_k(float* x, const float* __restrict__ g,
                                                     int C) {
  int t = blockIdx.x, tid = threadIdx.x;
  float* row = x + (long long)t * C;
  float ss = 0.f;
  for (int i = tid; i < C; i += 256) { float v = row[i]; ss += v * v; }
  __shared__ float red[4];
  ss = wave_sum64(ss);
  if ((tid & 63) == 0) red[tid >> 6] = ss;
  __syncthreads();
  float sc = rsqrtf((red[0] + red[1] + red[2] + red[3]) / (float)C + 1e-6f);
  for (int i = tid; i < C; i += 256) row[i] = row[i] * sc * g[i];
}

// ================= skv build -> bf16; row T_ = 0 =================
__global__ __launch_bounds__(256) void skv_build_k(const float* __restrict__ ckv,
                                                   const float* __restrict__ g,
                                                   const float* __restrict__ cosb,
                                                   const float* __restrict__ sinb,
                                                   __hip_bfloat16* __restrict__ skv) {
  int t = blockIdx.x, tid = threadIdx.x;
  __hip_bfloat16* out = skv + (long long)t * 576;
  if (t == T_) { for (int i = tid; i < 576; i += 256) out[i] = __float2bfloat16(0.f); return; }
  const float* row = ckv + (long long)t * 576;
  float ss = 0.f;
  for (int i = tid; i < 512; i += 256) { float v = row[i]; ss += v * v; }
  __shared__ float red[4];
  ss = wave_sum64(ss);
  if ((tid & 63) == 0) red[tid >> 6] = ss;
  __syncthreads();
  float sc = rsqrtf((red[0] + red[1] + red[2] + red[3]) / 512.f + 1e-6f);
  for (int i = tid; i < 512; i += 256) out[i] = __float2bfloat16(row[i] * sc * g[i]);
  if (tid < 64) {
    int j = tid, j2 = tid & 31;
    float c = cosb[t * 64 + j], s = sinb[t * 64 + j];
    float a = row[512 + 2 * j2], b = row[512 + 2 * j2 + 1];
    out[512 + j] = __float2bfloat16((j < 32) ? (a * c - b * s) : (a * s + b * c));
  }
}

// ================= rope in-place on qi heads (fp32) =================
__global__ __launch_bounds__(64) void rope_qi_k(float* qi, const float* __restrict__ cosb,
                                                const float* __restrict__ sinb) {
  int b = blockIdx.x, t = b >> 4, j = threadIdx.x, j2 = j & 31;
  float* x = qi + (long long)b * DI_;
  float c = cosb[t * 64 + j], s = sinb[t * 64 + j];
  float a = x[2 * j2], bb = x[2 * j2 + 1];
  float o = (j < 32) ? (a * c - bb * s) : (a * s + bb * c);
  x[j] = o;
}

// ================= ki: LayerNorm then rope, in-place (fp32) =================
__global__ __launch_bounds__(128) void ki_ln_rope_k(float* kbuf, const float* __restrict__ w,
                                                    const float* __restrict__ bia,
                                                    const float* __restrict__ cosb,
                                                    const float* __restrict__ sinb) {
  int t = blockIdx.x, i = threadIdx.x;
  float* row = kbuf + (long long)t * DI_;
  float x = row[i];
  __shared__ float red[2];
  float s1 = wave_sum64(x);
  if ((i & 63) == 0) red[i >> 6] = s1;
  __syncthreads();
  float mean = (red[0] + red[1]) / 128.f;
  float d = x - mean;
  __syncthreads();
  float s2 = wave_sum64(d * d);
  if ((i & 63) == 0) red[i >> 6] = s2;
  __syncthreads();
  float var = (red[0] + red[1]) / 128.f;
  float y = d * rsqrtf(var + 1e-6f) * w[i] + bia[i];
  __shared__ float rowl[128];
  rowl[i] = y;
  __syncthreads();
  float outv = y;
  if (i < 64) {
    int j2 = i & 31;
    float c = cosb[t * 64 + i], s = sinb[t * 64 + i];
    float a = rowl[2 * j2], b = rowl[2 * j2 + 1];
    outv = (i < 32) ? (a * c - b * s) : (a * s + b * c);
  }
  row[i] = outv;
}

// ================= rope q_full tail (bf16 in) -> sq_bf[...,512:576] =================
__global__ __launch_bounds__(64) void rope_q_sq_k(const __hip_bfloat16* __restrict__ qfull,
                                                  const float* __restrict__ cosb,
                                                  const float* __restrict__ sinb,
                                                  __hip_bfloat16* __restrict__ sq) {
  int b = blockIdx.x, t = b >> 4, h = b & 15, j = threadIdx.x, j2 = j & 31;
  const __hip_bfloat16* x = qfull + (long long)t * 3072 + h * 192 + 128;
  float c = cosb[t * 64 + j], s = sinb[t * 64 + j];
  float a = __bfloat162float(x[2 * j2]), bb = __bfloat162float(x[2 * j2 + 1]);
  float o = (j < 32) ? (a * c - bb * s) : (a * s + bb * c);
  sq[((long long)t * H_ + h) * 576 + 512 + j] = __float2bfloat16(o);
}

// ================= w = hidden @ i_wproj.T (fp32) =================
__global__ __launch_bounds__(256) void wproj_k(const float* __restrict__ hidden,
                                               const float* __restrict__ wp,
                                               float* __restrict__ out) {
  int wave = threadIdx.x >> 6, lane = threadIdx.x & 63;
  int t = blockIdx.x * 4 + wave;
  const float4* x4 = (const float4*)(hidden + (long long)t * 2048);
  float acc[16] = {};
  for (int c = lane; c < 512; c += 64) {
    float4 xv = x4[c];
#pragma unroll
    for (int h = 0; h < 16; ++h) {
      float4 wv = ((const float4*)(wp + h * 2048))[c];
      acc[h] += xv.x * wv.x + xv.y * wv.y + xv.z * wv.z + xv.w * wv.w;
    }
  }
#pragma unroll
  for (int h = 0; h < 16; ++h) {
    float s = wave_sum64(acc[h]);
    if (lane == 0) out[t * 16 + h] = s;
  }
}

// ================= indexer: MFMA bf16x3 scores + exact radix-select top-256 =================
// One block per query t. Scores fp32-accurate via hi/lo split; selection is the exact
// top-256 set with jax.lax.top_k tie-breaking (smallest index among equal scores).
__global__ __launch_bounds__(256) void score_topk_k(
    const short* __restrict__ qi_hi, const short* __restrict__ qi_lo,
    const short* __restrict__ ki_hi, const short* __restrict__ ki_lo,
    const float* __restrict__ wproj, const int* __restrict__ ks,
    const int* __restrict__ ke, int* __restrict__ indices)
{
  __shared__ float s_score[T_];
  __shared__ unsigned s_key[T_];
  __shared__ unsigned s_hist[256];
  __shared__ float s_w[HI_];
  __shared__ unsigned s_wsum[4];
  __shared__ unsigned s_binsel[2];
  __shared__ unsigned s_cnt;
  const int t = blockIdx.x, tid = threadIdx.x;
  const int wave = tid >> 6, lane = tid & 63;
  const int m0 = lane & 15, quad = lane >> 4;
  if (tid < HI_) s_w[tid] = wproj[t * HI_ + tid] * 0.022097086912079608f; // DI^-.5*HI^-.5
  if (tid == 0) s_cnt = 0;
  __syncthreads();

  // ---- scores: logits(16 heads x 1024 keys, K=128) via bf16x3 MFMA ----
  bfrag_t ah[4], al[4];
  {
    const short* qh = qi_hi + ((long long)t * HI_ + m0) * DI_ + quad * 8;
    const short* ql = qi_lo + ((long long)t * HI_ + m0) * DI_ + quad * 8;
#pragma unroll
    for (int k = 0; k < 4; ++k) {
      ah[k] = *(const bfrag_t*)(qh + k * 32);
      al[k] = *(const bfrag_t*)(ql + k * 32);
    }
  }
  const int lo = ks[t], hi = ke[t];
  for (int tt = 0; tt < 16; ++tt) {
    const int n0 = wave * 256 + tt * 16;
    const short* kh = ki_hi + (n0 + m0) * DI_ + quad * 8;
    const short* kl = ki_lo + (n0 + m0) * DI_ + quad * 8;
    f32x4 acc = {0.f, 0.f, 0.f, 0.f};
#pragma unroll
    for (int k = 0; k < 4; ++k) {
      bfrag_t bh = *(const bfrag_t*)(kh + k * 32);
      bfrag_t bl = *(const bfrag_t*)(kl + k * 32);
      acc = __builtin_amdgcn_mfma_f32_16x16x32_bf16(ah[k], bh, acc, 0, 0, 0);
      acc = __builtin_amdgcn_mfma_f32_16x16x32_bf16(ah[k], bl, acc, 0, 0, 0);
      acc = __builtin_amdgcn_mfma_f32_16x16x32_bf16(al[k], bh, acc, 0, 0, 0);
    }
    // acc[r] = logits[head = quad*4+r][key = n0+m0]; relu * w, reduce over heads
    float sc = 0.f;
#pragma unroll
    for (int r = 0; r < 4; ++r) sc += fmaxf(acc[r], 0.f) * s_w[quad * 4 + r];
    sc += __shfl_xor(sc, 16);
    sc += __shfl_xor(sc, 32);
    if (quad == 0) {
      int key = n0 + m0;
      s_score[key] = (key >= lo && key <= hi) ? sc : NEGF;
    }
  }
  __syncthreads();

  // ---- sortable keys (descending order = larger key) ----
  const int i0 = tid * 4;
#pragma unroll
  for (int j = 0; j < 4; ++j) {
    unsigned u = __float_as_uint(s_score[i0 + j]);
    s_key[i0 + j] = (u & 0x80000000u) ? ~u : (u | 0x80000000u);
  }
  __syncthreads();

  // ---- 4-level radix select: exact 32-bit threshold + strict-greater count ----
  unsigned prefix = 0, Gprev = 0;
  for (int lvl = 0; lvl < 4; ++lvl) {
    const int shift = 24 - 8 * lvl;
    s_hist[tid] = 0;
    __syncthreads();
#pragma unroll
    for (int j = 0; j < 4; ++j) {
      unsigned k = s_key[i0 + j];
      if (lvl == 0 || (k >> (shift + 8)) == prefix)
        atomicAdd(&s_hist[(k >> shift) & 255u], 1u);
    }
    __syncthreads();
    // cumulative count from highest bin downward (bin b handled by tid = 255-b)
    unsigned h = s_hist[255 - tid];
    unsigned sc_ = h;
    for (int off = 1; off < 64; off <<= 1) {
      unsigned v = __shfl_up(sc_, off);
      if (lane >= off) sc_ += v;
    }
    if (lane == 63) s_wsum[wave] = sc_;
    __syncthreads();
    unsigned wo = 0;
    for (int w = 0; w < wave; ++w) wo += s_wsum[w];
    unsigned incl = sc_ + wo, excl = incl - h;
    unsigned Rn = 256 - Gprev;
    if (excl < Rn && Rn <= incl) { s_binsel[0] = 255 - (unsigned)tid; s_binsel[1] = excl; }
    __syncthreads();
    prefix = (prefix << 8) | s_binsel[0];
    Gprev += s_binsel[1];
  }
  const unsigned thr = prefix;
  const unsigned Rq = 256 - Gprev;
  const unsigned negfkey = ~__float_as_uint(NEGF);

  // ---- ordered rank among equals (index order = top_k tie-break) ----
  unsigned eqc = 0;
#pragma unroll
  for (int j = 0; j < 4; ++j) eqc += (s_key[i0 + j] == thr) ? 1u : 0u;
  unsigned esc = eqc;
  for (int off = 1; off < 64; off <<= 1) {
    unsigned v = __shfl_up(esc, off);
    if (lane >= off) esc += v;
  }
  if (lane == 63) s_wsum[wave] = esc;
  __syncthreads();
  unsigned eo = 0;
  for (int w = 0; w < wave; ++w) eo += s_wsum[w];
  unsigned rank = esc + eo - eqc;

  // ---- compaction: strict-greater anywhere, equals in index order ----
#pragma unroll
  for (int j = 0; j < 4; ++j) {
    unsigned k = s_key[i0 + j];
    int outv = (k == negfkey) ? T_ : (i0 + j);
    if (k > thr) {
      unsigned slot = atomicAdd(&s_cnt, 1u);
      indices[t * TOPK_ + slot] = outv;
    } else if (k == thr) {
      if (rank < Rq) indices[t * TOPK_ + Gprev + rank] = outv;
      rank++;
    }
  }
}

// ================= MFMA gathered attention (verified R5) =================
#define SP_LD 257
#define PB_LD 264
__global__ __launch_bounds__(256) void attn_k(
    const short* __restrict__ sq, const short* __restrict__ skv,
    const int* __restrict__ indices, __hip_bfloat16* __restrict__ attn_out)
{
  __shared__ int s_ind[TOPK_];
  __shared__ float s_p[H_ * SP_LD];
  __shared__ short s_pb[H_ * PB_LD];
  __shared__ short s_vt[64 * PB_LD];
  const int t = blockIdx.x, tid = threadIdx.x;
  const int wave = tid >> 6, lane = tid & 63;
  const int m0 = lane & 15, quad = lane >> 4;
  s_ind[tid] = indices[t * TOPK_ + tid];
  __syncthreads();

  {
    const int jb = wave * 64;
    int rows[4];
    const short* kvp[4];
#pragma unroll
    for (int j = 0; j < 4; ++j) {
      rows[j] = s_ind[jb + j * 16 + m0];
      kvp[j] = skv + rows[j] * 576 + quad * 8;
    }
    const short* qp = sq + ((long long)t * H_ + m0) * 576 + quad * 8;
    f32x4 qacc[4] = {};
    for (int ks = 0; ks < 18; ++ks) {
      const int k0 = ks * 32;
      bfrag_t aq = *(const bfrag_t*)(qp + k0);
#pragma unroll
      for (int j = 0; j < 4; ++j) {
        bfrag_t bq = *(const bfrag_t*)(kvp[j] + k0);
        qacc[j] = __builtin_amdgcn_mfma_f32_16x16x32_bf16(aq, bq, qacc[j], 0, 0, 0);
      }
    }
    const float scale = 0.07216878364870322f;
#pragma unroll
    for (int j = 0; j < 4; ++j) {
      int key = jb + j * 16 + m0;
      bool msk = (rows[j] == T_);
#pragma unroll
      for (int r = 0; r < 4; ++r)
        s_p[(quad * 4 + r) * SP_LD + key] = msk ? NEGF : qacc[j][r] * scale;
    }
  }
  __syncthreads();

  for (int h = wave * 4; h < wave * 4 + 4; ++h) {
    float* ph = s_p + h * SP_LD;
    float m = -3.4e38f;
    for (int j = lane; j < TOPK_; j += 64) m = fmaxf(m, ph[j]);
#pragma unroll
    for (int off = 32; off; off >>= 1) m = fmaxf(m, __shfl_xor(m, off));
    float sum = 0.f;
    for (int j = lane; j < TOPK_; j += 64) {
      float e = __expf(ph[j] - m);
      ph[j] = e; sum += e;
    }
    sum = wave_sum64(sum);
    float inv = 1.f / sum;
    for (int j = lane; j < TOPK_; j += 64) ph[j] *= inv;
  }
  __syncthreads();

#pragma unroll
  for (int h = 0; h < H_; ++h)
    s_pb[h * PB_LD + tid] = (short)__bfloat16_as_ushort(__float2bfloat16(s_p[h * SP_LD + tid]));
  __syncthreads();

  bfrag_t apf[8];
#pragma unroll
  for (int kk = 0; kk < 8; ++kk)
    apf[kk] = *(const bfrag_t*)(s_pb + m0 * PB_LD + kk * 32 + quad * 8);

  const int myrow = s_ind[tid];
  const short* vsrc = skv + myrow * 576;

  for (int c = 0; c < 8; ++c) {
    const int c0 = c * 64;
#pragma unroll
    for (int b = 0; b < 8; ++b) {
      bfrag_t v = *(const bfrag_t*)(vsrc + c0 + b * 8);
#pragma unroll
      for (int j = 0; j < 8; ++j)
        s_vt[(b * 8 + j) * PB_LD + tid] = v[j];
    }
    __syncthreads();
    const short* vb = s_vt + (wave * 16 + m0) * PB_LD + quad * 8;
    f32x4 oacc = {0.f, 0.f, 0.f, 0.f};
#pragma unroll
    for (int kk = 0; kk < 8; ++kk) {
      bfrag_t bv = *(const bfrag_t*)(vb + kk * 32);
      oacc = __builtin_amdgcn_mfma_f32_16x16x32_bf16(apf[kk], bv, oacc, 0, 0, 0);
    }
    const int col = c0 + wave * 16 + m0;
#pragma unroll
    for (int r = 0; r < 4; ++r)
      attn_out[((long long)t * H_ + quad * 4 + r) * 512 + col] = __float2bfloat16(oacc[r]);
    __syncthreads();
  }
}

extern "C" void kernel_launch(void* const* d_in, const int* in_sizes, int n_in,
                              void* d_out, int out_size, void* d_ws, size_t ws_size,
                              hipStream_t stream) {
  const float* hidden  = (const float*)d_in[0];
  const float* cosb    = (const float*)d_in[1];
  const float* sinb    = (const float*)d_in[2];
  const int*   ks      = (const int*)d_in[3];
  const int*   ke      = (const int*)d_in[4];
  const float* w_qa    = (const float*)d_in[5];
  const float* g_qa    = (const float*)d_in[6];
  const float* w_qb    = (const float*)d_in[7];
  const float* w_kva   = (const float*)d_in[8];
  const float* g_kva   = (const float*)d_in[9];
  const float* w_kvb   = (const float*)d_in[10];
  const float* w_o     = (const float*)d_in[11];
  const float* i_wqb   = (const float*)d_in[12];
  const float* i_wk    = (const float*)d_in[13];
  const float* i_ln_w  = (const float*)d_in[14];
  const float* i_ln_b  = (const float*)d_in[15];
  const float* i_wproj = (const float*)d_in[16];
  float* out = (float*)d_out;
  (void)in_sizes; (void)n_in; (void)out_size; (void)ws_size;

  // ---- workspace (bytes), lifetime-overlapped ----
  char* ws = (char*)d_ws;
  __hip_bfloat16* hid_hi  = (__hip_bfloat16*)(ws + 0);          // 4 MB   [dead after ki gemm3]
  __hip_bfloat16* hid_lo  = (__hip_bfloat16*)(ws + 4194304);    // 4 MB
  float*          q_lat   = (float*)(ws + 8388608);             // 6.3 MB [dead after qlat decomp]
  __hip_bfloat16* qi_hi   = (__hip_bfloat16*)(ws + 8388608);    // 4 MB   [over dead q_lat... NO: q_lat needed until decomp]
  __hip_bfloat16* qlat_hi = (__hip_bfloat16*)(ws + 14680064);   // 3 MB   [dead after q_full]
  __hip_bfloat16* qlat_lo = (__hip_bfloat16*)(ws + 17825792);   // 3 MB
  float*          qi      = (float*)(ws + 20971520);            // 8 MB   [dead after qi decomp]
  float*          kib     = (float*)(ws + 29360128);            // 0.5 MB [dead after ki decomp]
  float*          wbuf    = (float*)(ws + 29884416);            // 64 KB  [dead after topk]
  float*          ckv     = (float*)(ws + 29949952);            // 2.3 MB [dead after skv]
  __hip_bfloat16* qi_lo   = (__hip_bfloat16*)(ws + 29949952);   // 4 MB   [over dead ckv; dead after topk]
  __hip_bfloat16* ki_hi   = (__hip_bfloat16*)(ws + 34144256);   // 256 KB [dead after topk]
  __hip_bfloat16* ki_lo   = (__hip_bfloat16*)(ws + 34406400);   // 256 KB [dead after topk]
  __hip_bfloat16* sq_bf   = (__hip_bfloat16*)(ws + 0);          // 18.9 MB [after region A dead]
  __hip_bfloat16* o_bf    = (__hip_bfloat16*)(ws + 0);          // 4 MB   [after sq_bf dead]
  __hip_bfloat16* W       = (__hip_bfloat16*)(ws + 37748736);   // 9.4 MB weight hi-buffer
  __hip_bfloat16* skv_bf  = (__hip_bfloat16*)(ws + 47185920);   // 1.18 MB
  int*            idxb    = (int*)(ws + 48366720);              // 1 MB
  __hip_bfloat16* E       = (__hip_bfloat16*)(ws + 49415296);   // 16.7 MB: Wlo / qfull / attn_bf
  // NOTE: qi_hi aliases q_lat's region but is written (qi decomp) only after
  // qlat decomp has consumed q_lat. qi_hi is 4 MB at 8388608..12582912, inside
  // q_lat's 8388608..14680064; q_lat dead at that point. sq_bf (0..18.9MB) is
  // written only after topk (qi_hi dead) and after q_full gemm (qlat_hi dead).

  dim3 blk(256);
  const short* Ws = (const short*)W;
  const short* Es = (const short*)E;

  // hidden -> hi/lo
  decomp_k<<<2048, blk, 0, stream>>>(hidden, hid_hi, hid_lo, 524288);

  // q_lat = hidden @ w_qa.T (bf16x3); RMS fp32
  decomp_k<<<3072, blk, 0, stream>>>(w_qa, W, E, 786432);
  gemm3_k<<<dim3(12, 8), blk, 0, stream>>>(
      (const short*)hid_hi, (const short*)hid_lo, HID_, Ws, Es, HID_, q_lat, LQ_, LQ_, HID_);
  rms_inplace_k<<<T_, blk, 0, stream>>>(q_lat, g_qa, LQ_);

  // ckv = hidden @ w_kva.T (bf16), skv build -> bf16
  cast_pad_k<<<1280, blk, 0, stream>>>(w_kva, W, 576, 512, 640);
  gemm_bf_k<float><<<dim3(5, 8, 1), blk, 0, stream>>>(
      (const short*)hid_hi, HID_, 0, Ws, HID_, 0, ckv, 576, 0, 576, HID_);
  skv_build_k<<<T_ + 1, blk, 0, stream>>>(ckv, g_kva, cosb, sinb, skv_bf);

  // q_lat -> hi/lo (q_lat dead after this)
  decomp_k<<<1536, blk, 0, stream>>>(q_lat, qlat_hi, qlat_lo, 393216);

  // qi = q_lat @ i_wqb.T (bf16x3), rope, decomp -> qi_hi/lo
  decomp_k<<<3072, blk, 0, stream>>>(i_wqb, W, E, 786432);
  gemm3_k<<<dim3(16, 8), blk, 0, stream>>>(
      (const short*)qlat_hi, (const short*)qlat_lo, LQ_, Ws, Es, LQ_, qi, HI_ * DI_, HI_ * DI_, LQ_);
  rope_qi_k<<<T_ * HI_, dim3(64), 0, stream>>>(qi, cosb, sinb);
  decomp_k<<<2048, blk, 0, stream>>>(qi, qi_hi, qi_lo, 524288);

  // ki = hidden @ i_wk.T (bf16x3), LN + rope, decomp -> ki_hi/lo
  decomp_k<<<256, blk, 0, stream>>>(i_wk, W, E, 65536);
  gemm3_k<<<dim3(1, 8), blk, 0, stream>>>(
      (const short*)hid_hi, (const short*)hid_lo, HID_, Ws, Es, HID_, kib, DI_, DI_, HID_);
  ki_ln_rope_k<<<T_, dim3(128), 0, stream>>>(kib, i_ln_w, i_ln_b, cosb, sinb);
  decomp_k<<<128, blk, 0, stream>>>(kib, ki_hi, ki_lo, 32768);

  // w = hidden @ i_wproj.T (fp32)
  wproj_k<<<256, blk, 0, stream>>>(hidden, i_wproj, wbuf);

  // indexer: MFMA scores + radix-select top-256
  score_topk_k<<<T_, blk, 0, stream>>>(
      (const short*)qi_hi, (const short*)qi_lo, (const short*)ki_hi, (const short*)ki_lo,
      wbuf, ks, ke, idxb);

  // q_full = q_lat @ w_qb.T (bf16 -> E), rope tail -> sq_bf
  cast_bf16_k<<<4608, blk, 0, stream>>>(w_qb, W, 1179648);
  gemm_bf_k<__hip_bfloat16><<<dim3(24, 8, 1), blk, 0, stream>>>(
      (const short*)qlat_hi, LQ_, 0, Ws, LQ_, 0, (__hip_bfloat16*)E, H_ * DQ_, 0, H_ * DQ_, LQ_);
  rope_q_sq_k<<<T_ * H_, dim3(64), 0, stream>>>(E, cosb, sinb, sq_bf);

  // q_abs = q_nope @ w_kn per head -> sq_bf[...,0:512] (bf16)
  wkn_t_k<<<4096, blk, 0, stream>>>(w_kvb, W);
  gemm_bf_k<__hip_bfloat16><<<dim3(4, 8, 16), blk, 0, stream>>>(
      Es, H_ * DQ_, 192, Ws, DI_, 65536, sq_bf, H_ * 576, 576, LKV_, DN_);

  // MFMA gathered attention -> E (bf16)
  attn_k<<<T_, blk, 0, stream>>>((const short*)sq_bf, (const short*)skv_bf, idxb, E);

  // o = attn @ w_v.T per head -> o_bf
  wv_cast_k<<<4096, blk, 0, stream>>>(w_kvb, W);
  gemm_bf_k<__hip_bfloat16><<<dim3(1, 8, 16), blk, 0, stream>>>(
      Es, H_ * LKV_, 512, Ws, LKV_, 65536, o_bf, H_ * DV_, 128, DV_, LKV_);

  // final = o @ w_o.T -> out (fp32)
  cast_bf16_k<<<4096, blk, 0, stream>>>(w_o, W, 1048576);
  gemm_bf_k<float><<<dim3(16, 8, 1), blk, 0, stream>>>(
      (const short*)o_bf, H_ * DV_, 0, Ws, H_ * DV_, 0, out, HID_, 0, HID_, H_ * DV_);
}

// Round 7
// 709.063 us; speedup vs baseline: 3.6478x; 1.0491x over previous
//
#include <hip/hip_runtime.h>
#include <hip/hip_bf16.h>
#include <cmath>

#define T_ 1024
#define HID_ 2048
#define H_ 16
#define LQ_ 1536
#define LKV_ 512
#define DR_ 64
#define DN_ 128
#define DQ_ 192
#define DV_ 128
#define HI_ 16
#define DI_ 128
#define TOPK_ 256
#define NEGF (-1e30f)

typedef short bfrag_t __attribute__((ext_vector_type(8)));   // 8 bf16 = 4 VGPRs
typedef float f32x4 __attribute__((ext_vector_type(4)));

__device__ __forceinline__ float wave_sum64(float v) {
#pragma unroll
  for (int off = 32; off; off >>= 1) v += __shfl_xor(v, off);
  return v;
}

#define GLL(g, l) __builtin_amdgcn_global_load_lds((const __attribute__((address_space(1))) void*)(g), \
                                     (__attribute__((address_space(3))) void*)(l), 16, 0, 0)

// ================= bf16 MFMA GEMM: C = A @ B^T — double-buffered, raw-barrier pipeline ====
// stage(k+1) -> s_waitcnt vmcnt(4) (waits only tile k's loads) -> s_barrier -> MFMA(k) -> s_barrier
template<typename CT>
__global__ __launch_bounds__(256) void gemm_bf_k(
    const short* __restrict__ A, int lda, long long sA,
    const short* __restrict__ B, int ldb, long long sB,
    CT* __restrict__ C, int ldc, long long sC,
    int Nout, int K)
{
  __shared__ short As[2][128 * 32];
  __shared__ short Bs[2][128 * 32];
  A += (long long)blockIdx.z * sA;
  B += (long long)blockIdx.z * sB;
  C += (long long)blockIdx.z * sC;
  const int tid = threadIdx.x;
  const int bm = blockIdx.y * 128, bn = blockIdx.x * 128;
  const int wave = tid >> 6, lane = tid & 63;
  const int wm = (wave >> 1) * 64, wn = (wave & 1) * 64;
  const int sr = tid >> 2;
  const int scol = (tid & 3) * 8;
  const int m0 = lane & 15, koff = (lane >> 4) * 8;
  f32x4 acc[4][4] = {};
  const short* ga = A + (long long)(bm + sr) * lda + scol;
  const short* gb = B + (long long)(bn + sr) * ldb + scol;
#define STAGE_BF(buf, off) \
    GLL(ga + (off), As[buf] + tid * 8); GLL(ga + (off) + 64 * lda, As[buf] + tid * 8 + 2048); \
    GLL(gb + (off), Bs[buf] + tid * 8); GLL(gb + (off) + 64 * ldb, Bs[buf] + tid * 8 + 2048);
  const int niter = K >> 5;
  STAGE_BF(0, 0);
  for (int it = 0; it < niter; ++it) {
    const int cur = it & 1;
    if (it + 1 < niter) {
      STAGE_BF(cur ^ 1, (it + 1) * 32);
      asm volatile("s_waitcnt vmcnt(4)\ns_barrier" ::: "memory");
    } else {
      asm volatile("s_waitcnt vmcnt(0)\ns_barrier" ::: "memory");
    }
    bfrag_t af[4], bfv[4];
#pragma unroll
    for (int i = 0; i < 4; ++i)
      af[i] = *(const bfrag_t*)(As[cur] + (wm + i * 16 + m0) * 32 + koff);
#pragma unroll
    for (int j = 0; j < 4; ++j)
      bfv[j] = *(const bfrag_t*)(Bs[cur] + (wn + j * 16 + m0) * 32 + koff);
#pragma unroll
    for (int i = 0; i < 4; ++i)
#pragma unroll
      for (int j = 0; j < 4; ++j)
        acc[i][j] = __builtin_amdgcn_mfma_f32_16x16x32_bf16(af[i], bfv[j], acc[i][j], 0, 0, 0);
    asm volatile("s_barrier" ::: "memory");
  }
#undef STAGE_BF
  const int cr = (lane >> 4) * 4, cc = lane & 15;
#pragma unroll
  for (int i = 0; i < 4; ++i) {
    int row = bm + wm + i * 16 + cr;
#pragma unroll
    for (int j = 0; j < 4; ++j) {
      int col = bn + wn + j * 16 + cc;
      if (col < Nout) {
#pragma unroll
        for (int r = 0; r < 4; ++r)
          C[(long long)(row + r) * ldc + col] = (CT)(acc[i][j][r]);
      }
    }
  }
}

// ====== bf16x3 split GEMM (fp32-accurate) — same double-buffered pipeline, vmcnt(8) ======
__global__ __launch_bounds__(256) void gemm3_k(
    const short* __restrict__ Ah, const short* __restrict__ Al, int lda,
    const short* __restrict__ Bh, const short* __restrict__ Bl, int ldb,
    float* __restrict__ C, int ldc, int Nout, int K)
{
  __shared__ short Ahs[2][128 * 32];
  __shared__ short Als[2][128 * 32];
  __shared__ short Bhs[2][128 * 32];
  __shared__ short Bls[2][128 * 32];
  const int tid = threadIdx.x;
  const int bm = blockIdx.y * 128, bn = blockIdx.x * 128;
  const int wave = tid >> 6, lane = tid & 63;
  const int wm = (wave >> 1) * 64, wn = (wave & 1) * 64;
  const int sr = tid >> 2;
  const int scol = (tid & 3) * 8;
  const int m0 = lane & 15, koff = (lane >> 4) * 8;
  f32x4 acc[4][4] = {};
  const short* gah = Ah + (long long)(bm + sr) * lda + scol;
  const short* gal = Al + (long long)(bm + sr) * lda + scol;
  const short* gbh = Bh + (long long)(bn + sr) * ldb + scol;
  const short* gbl = Bl + (long long)(bn + sr) * ldb + scol;
#define STAGE_3(buf, off) \
    GLL(gah + (off), Ahs[buf] + tid * 8); GLL(gah + (off) + 64 * lda, Ahs[buf] + tid * 8 + 2048); \
    GLL(gal + (off), Als[buf] + tid * 8); GLL(gal + (off) + 64 * lda, Als[buf] + tid * 8 + 2048); \
    GLL(gbh + (off), Bhs[buf] + tid * 8); GLL(gbh + (off) + 64 * ldb, Bhs[buf] + tid * 8 + 2048); \
    GLL(gbl + (off), Bls[buf] + tid * 8); GLL(gbl + (off) + 64 * ldb, Bls[buf] + tid * 8 + 2048);
  const int niter = K >> 5;
  STAGE_3(0, 0);
  for (int it = 0; it < niter; ++it) {
    const int cur = it & 1;
    if (it + 1 < niter) {
      STAGE_3(cur ^ 1, (it + 1) * 32);
      asm volatile("s_waitcnt vmcnt(8)\ns_barrier" ::: "memory");
    } else {
      asm volatile("s_waitcnt vmcnt(0)\ns_barrier" ::: "memory");
    }
    bfrag_t afh[4], afl[4], bfh[4], bfl[4];
#pragma unroll
    for (int i = 0; i < 4; ++i) {
      afh[i] = *(const bfrag_t*)(Ahs[cur] + (wm + i * 16 + m0) * 32 + koff);
      afl[i] = *(const bfrag_t*)(Als[cur] + (wm + i * 16 + m0) * 32 + koff);
    }
#pragma unroll
    for (int j = 0; j < 4; ++j) {
      bfh[j] = *(const bfrag_t*)(Bhs[cur] + (wn + j * 16 + m0) * 32 + koff);
      bfl[j] = *(const bfrag_t*)(Bls[cur] + (wn + j * 16 + m0) * 32 + koff);
    }
#pragma unroll
    for (int i = 0; i < 4; ++i)
#pragma unroll
      for (int j = 0; j < 4; ++j) {
        acc[i][j] = __builtin_amdgcn_mfma_f32_16x16x32_bf16(afh[i], bfh[j], acc[i][j], 0, 0, 0);
        acc[i][j] = __builtin_amdgcn_mfma_f32_16x16x32_bf16(afh[i], bfl[j], acc[i][j], 0, 0, 0);
        acc[i][j] = __builtin_amdgcn_mfma_f32_16x16x32_bf16(afl[i], bfh[j], acc[i][j], 0, 0, 0);
      }
    asm volatile("s_barrier" ::: "memory");
  }
#undef STAGE_3
  const int cr = (lane >> 4) * 4, cc = lane & 15;
#pragma unroll
  for (int i = 0; i < 4; ++i) {
    int row = bm + wm + i * 16 + cr;
#pragma unroll
    for (int j = 0; j < 4; ++j) {
      int col = bn + wn + j * 16 + cc;
      if (col < Nout) {
#pragma unroll
        for (int r = 0; r < 4; ++r)
          C[(long long)(row + r) * ldc + col] = acc[i][j][r];
      }
    }
  }
}

// ================= casts / decompose =================
__global__ __launch_bounds__(256) void cast_bf16_k(const float* __restrict__ src,
                                                   __hip_bfloat16* __restrict__ dst, int n4) {
  int i = blockIdx.x * 256 + threadIdx.x;
  if (i >= n4) return;
  float4 v = ((const float4*)src)[i];
  union { ushort4 u; __hip_bfloat16 h[4]; } o;
  o.h[0] = __float2bfloat16(v.x); o.h[1] = __float2bfloat16(v.y);
  o.h[2] = __float2bfloat16(v.z); o.h[3] = __float2bfloat16(v.w);
  ((ushort4*)dst)[i] = o.u;
}

__global__ __launch_bounds__(256) void decomp_k(const float* __restrict__ src,
                                                __hip_bfloat16* __restrict__ hi,
                                                __hip_bfloat16* __restrict__ lo, int n4) {
  int i = blockIdx.x * 256 + threadIdx.x;
  if (i >= n4) return;
  float4 v = ((const float4*)src)[i];
  float f[4] = {v.x, v.y, v.z, v.w};
  union { ushort4 u; __hip_bfloat16 h[4]; } oh, ol;
#pragma unroll
  for (int j = 0; j < 4; ++j) {
    __hip_bfloat16 h = __float2bfloat16(f[j]);
    oh.h[j] = h;
    ol.h[j] = __float2bfloat16(f[j] - __bfloat162float(h));
  }
  ((ushort4*)hi)[i] = oh.u;
  ((ushort4*)lo)[i] = ol.u;
}

__global__ __launch_bounds__(256) void cast_pad_k(const float* __restrict__ src,
                                                  __hip_bfloat16* __restrict__ dst,
                                                  int N, int K4, int Npad) {
  int i = blockIdx.x * 256 + threadIdx.x;
  if (i >= Npad * K4) return;
  int r = i / K4;
  float4 v = make_float4(0.f, 0.f, 0.f, 0.f);
  if (r < N) v = ((const float4*)src)[i];
  union { ushort4 u; __hip_bfloat16 h[4]; } o;
  o.h[0] = __float2bfloat16(v.x); o.h[1] = __float2bfloat16(v.y);
  o.h[2] = __float2bfloat16(v.z); o.h[3] = __float2bfloat16(v.w);
  ((ushort4*)dst)[i] = o.u;
}

// w_kn transposed-cast via LDS 64x64 tile: dst[h][k][d] = w_kvb[(h*256+d)*512+k]
__global__ __launch_bounds__(256) void wkn_t_k(const float* __restrict__ wkvb,
                                               __hip_bfloat16* __restrict__ dst) {
  __shared__ float tile[64][65];
  const int h = blockIdx.z, k0 = blockIdx.y * 64, d0 = blockIdx.x * 64;
  const int c = threadIdx.x & 63, r0 = threadIdx.x >> 6;
#pragma unroll
  for (int rr = 0; rr < 16; ++rr) {
    int r = r0 + rr * 4;
    tile[r][c] = wkvb[((h * 256 + d0 + r) << 9) + k0 + c];  // coalesced (k fast)
  }
  __syncthreads();
#pragma unroll
  for (int rr = 0; rr < 16; ++rr) {
    int r = r0 + rr * 4;   // k-local
    dst[((h * 512 + k0 + r) << 7) + d0 + c] = __float2bfloat16(tile[c][r]); // coalesced (d fast)
  }
}

__global__ __launch_bounds__(256) void wv_cast_k(const float* __restrict__ wkvb,
                                                 __hip_bfloat16* __restrict__ dst) {
  int i = blockIdx.x * 256 + threadIdx.x;
  int k = i & 511, dv = (i >> 9) & 127, h = i >> 16;
  dst[i] = __float2bfloat16(wkvb[((h * 256 + 128 + dv) << 9) + k]);
}

// ================= RMSNorm in-place (fp32) =================
__global__ __launch_bounds__(256) void rms_inplace_k(float* x, const float* __restrict__ g,
                                                     int C) {
  int t = blockIdx.x, tid = threadIdx.x;
  float* row = x + (long long)t * C;
  float ss = 0.f;
  for (int i = tid; i < C; i += 256) { float v = row[i]; ss += v * v; }
  __shared__ float red[4];
  ss = wave_sum64(ss);
  if ((tid & 63) == 0) red[tid >> 6] = ss;
  __syncthreads();
  float sc = rsqrtf((red[0] + red[1] + red[2] + red[3]) / (float)C + 1e-6f);
  for (int i = tid; i < C; i += 256) row[i] = row[i] * sc * g[i];
}

// ================= skv build -> bf16; row T_ = 0 =================
__global__ __launch_bounds__(256) void skv_build_k(const float* __restrict__ ckv,
                                                   const float* __restrict__ g,
                                                   const float* __restrict__ cosb,
                                                   const float* __restrict__ sinb,
                                                   __hip_bfloat16* __restrict__ skv) {
  int t = blockIdx.x, tid = threadIdx.x;
  __hip_bfloat16* out = skv + (long long)t * 576;
  if (t == T_) { for (int i = tid; i < 576; i += 256) out[i] = __float2bfloat16(0.f); return; }
  const float* row = ckv + (long long)t * 576;
  float ss = 0.f;
  for (int i = tid; i < 512; i += 256) { float v = row[i]; ss += v * v; }
  __shared__ float red[4];
  ss = wave_sum64(ss);
  if ((tid & 63) == 0) red[tid >> 6] = ss;
  __syncthreads();
  float sc = rsqrtf((red[0] + red[1] + red[2] + red[3]) / 512.f + 1e-6f);
  for (int i = tid; i < 512; i += 256) out[i] = __float2bfloat16(row[i] * sc * g[i]);
  if (tid < 64) {
    int j = tid, j2 = tid & 31;
    float c = cosb[t * 64 + j], s = sinb[t * 64 + j];
    float a = row[512 + 2 * j2], b = row[512 + 2 * j2 + 1];
    out[512 + j] = __float2bfloat16((j < 32) ? (a * c - b * s) : (a * s + b * c));
  }
}

// ================= rope in-place on qi heads (fp32) =================
__global__ __launch_bounds__(64) void rope_qi_k(float* qi, const float* __restrict__ cosb,
                                                const float* __restrict__ sinb) {
  int b = blockIdx.x, t = b >> 4, j = threadIdx.x, j2 = j & 31;
  float* x = qi + (long long)b * DI_;
  float c = cosb[t * 64 + j], s = sinb[t * 64 + j];
  float a = x[2 * j2], bb = x[2 * j2 + 1];
  float o = (j < 32) ? (a * c - bb * s) : (a * s + bb * c);
  x[j] = o;
}

// ================= ki: LayerNorm then rope, in-place (fp32) =================
__global__ __launch_bounds__(128) void ki_ln_rope_k(float* kbuf, const float* __restrict__ w,
                                                    const float* __restrict__ bia,
                                                    const float* __restrict__ cosb,
                                                    const float* __restrict__ sinb) {
  int t = blockIdx.x, i = threadIdx.x;
  float* row = kbuf + (long long)t * DI_;
  float x = row[i];
  __shared__ float red[2];
  float s1 = wave_sum64(x);
  if ((i & 63) == 0) red[i >> 6] = s1;
  __syncthreads();
  float mean = (red[0] + red[1]) / 128.f;
  float d = x - mean;
  __syncthreads();
  float s2 = wave_sum64(d * d);
  if ((i & 63) == 0) red[i >> 6] = s2;
  __syncthreads();
  float var = (red[0] + red[1]) / 128.f;
  float y = d * rsqrtf(var + 1e-6f) * w[i] + bia[i];
  __shared__ float rowl[128];
  rowl[i] = y;
  __syncthreads();
  float outv = y;
  if (i < 64) {
    int j2 = i & 31;
    float c = cosb[t * 64 + i], s = sinb[t * 64 + i];
    float a = rowl[2 * j2], b = rowl[2 * j2 + 1];
    outv = (i < 32) ? (a * c - b * s) : (a * s + b * c);
  }
  row[i] = outv;
}

// ================= rope q_full tail (bf16 in) -> sq_bf[...,512:576] =================
__global__ __launch_bounds__(64) void rope_q_sq_k(const __hip_bfloat16* __restrict__ qfull,
                                                  const float* __restrict__ cosb,
                                                  const float* __restrict__ sinb,
                                                  __hip_bfloat16* __restrict__ sq) {
  int b = blockIdx.x, t = b >> 4, h = b & 15, j = threadIdx.x, j2 = j & 31;
  const __hip_bfloat16* x = qfull + (long long)t * 3072 + h * 192 + 128;
  float c = cosb[t * 64 + j], s = sinb[t * 64 + j];
  float a = __bfloat162float(x[2 * j2]), bb = __bfloat162float(x[2 * j2 + 1]);
  float o = (j < 32) ? (a * c - bb * s) : (a * s + bb * c);
  sq[((long long)t * H_ + h) * 576 + 512 + j] = __float2bfloat16(o);
}

// ================= w = hidden @ i_wproj.T (fp32) =================
__global__ __launch_bounds__(256) void wproj_k(const float* __restrict__ hidden,
                                               const float* __restrict__ wp,
                                               float* __restrict__ out) {
  int wave = threadIdx.x >> 6, lane = threadIdx.x & 63;
  int t = blockIdx.x * 4 + wave;
  const float4* x4 = (const float4*)(hidden + (long long)t * 2048);
  float acc[16] = {};
  for (int c = lane; c < 512; c += 64) {
    float4 xv = x4[c];
#pragma unroll
    for (int h = 0; h < 16; ++h) {
      float4 wv = ((const float4*)(wp + h * 2048))[c];
      acc[h] += xv.x * wv.x + xv.y * wv.y + xv.z * wv.z + xv.w * wv.w;
    }
  }
#pragma unroll
  for (int h = 0; h < 16; ++h) {
    float s = wave_sum64(acc[h]);
    if (lane == 0) out[t * 16 + h] = s;
  }
}

// ================= indexer: MFMA bf16x3 scores + exact radix-select top-256 (verified R6) ===
__global__ __launch_bounds__(256) void score_topk_k(
    const short* __restrict__ qi_hi, const short* __restrict__ qi_lo,
    const short* __restrict__ ki_hi, const short* __restrict__ ki_lo,
    const float* __restrict__ wproj, const int* __restrict__ ks,
    const int* __restrict__ ke, int* __restrict__ indices)
{
  __shared__ float s_score[T_];
  __shared__ unsigned s_key[T_];
  __shared__ unsigned s_hist[256];
  __shared__ float s_w[HI_];
  __shared__ unsigned s_wsum[4];
  __shared__ unsigned s_binsel[2];
  __shared__ unsigned s_cnt;
  const int t = blockIdx.x, tid = threadIdx.x;
  const int wave = tid >> 6, lane = tid & 63;
  const int m0 = lane & 15, quad = lane >> 4;
  if (tid < HI_) s_w[tid] = wproj[t * HI_ + tid] * 0.022097086912079608f;
  if (tid == 0) s_cnt = 0;
  __syncthreads();

  bfrag_t ah[4], al[4];
  {
    const short* qh = qi_hi + ((long long)t * HI_ + m0) * DI_ + quad * 8;
    const short* ql = qi_lo + ((long long)t * HI_ + m0) * DI_ + quad * 8;
#pragma unroll
    for (int k = 0; k < 4; ++k) {
      ah[k] = *(const bfrag_t*)(qh + k * 32);
      al[k] = *(const bfrag_t*)(ql + k * 32);
    }
  }
  const int lo = ks[t], hi = ke[t];
  for (int tt = 0; tt < 16; ++tt) {
    const int n0 = wave * 256 + tt * 16;
    const short* kh = ki_hi + (n0 + m0) * DI_ + quad * 8;
    const short* kl = ki_lo + (n0 + m0) * DI_ + quad * 8;
    f32x4 acc = {0.f, 0.f, 0.f, 0.f};
#pragma unroll
    for (int k = 0; k < 4; ++k) {
      bfrag_t bh = *(const bfrag_t*)(kh + k * 32);
      bfrag_t bl = *(const bfrag_t*)(kl + k * 32);
      acc = __builtin_amdgcn_mfma_f32_16x16x32_bf16(ah[k], bh, acc, 0, 0, 0);
      acc = __builtin_amdgcn_mfma_f32_16x16x32_bf16(ah[k], bl, acc, 0, 0, 0);
      acc = __builtin_amdgcn_mfma_f32_16x16x32_bf16(al[k], bh, acc, 0, 0, 0);
    }
    float sc = 0.f;
#pragma unroll
    for (int r = 0; r < 4; ++r) sc += fmaxf(acc[r], 0.f) * s_w[quad * 4 + r];
    sc += __shfl_xor(sc, 16);
    sc += __shfl_xor(sc, 32);
    if (quad == 0) {
      int key = n0 + m0;
      s_score[key] = (key >= lo && key <= hi) ? sc : NEGF;
    }
  }
  __syncthreads();

  const int i0 = tid * 4;
#pragma unroll
  for (int j = 0; j < 4; ++j) {
    unsigned u = __float_as_uint(s_score[i0 + j]);
    s_key[i0 + j] = (u & 0x80000000u) ? ~u : (u | 0x80000000u);
  }
  __syncthreads();

  unsigned prefix = 0, Gprev = 0;
  for (int lvl = 0; lvl < 4; ++lvl) {
    const int shift = 24 - 8 * lvl;
    s_hist[tid] = 0;
    __syncthreads();
#pragma unroll
    for (int j = 0; j < 4; ++j) {
      unsigned k = s_key[i0 + j];
      if (lvl == 0 || (k >> (shift + 8)) == prefix)
        atomicAdd(&s_hist[(k >> shift) & 255u], 1u);
    }
    __syncthreads();
    unsigned h = s_hist[255 - tid];
    unsigned sc_ = h;
    for (int off = 1; off < 64; off <<= 1) {
      unsigned v = __shfl_up(sc_, off);
      if (lane >= off) sc_ += v;
    }
    if (lane == 63) s_wsum[wave] = sc_;
    __syncthreads();
    unsigned wo = 0;
    for (int w = 0; w < wave; ++w) wo += s_wsum[w];
    unsigned incl = sc_ + wo, excl = incl - h;
    unsigned Rn = 256 - Gprev;
    if (excl < Rn && Rn <= incl) { s_binsel[0] = 255 - (unsigned)tid; s_binsel[1] = excl; }
    __syncthreads();
    prefix = (prefix << 8) | s_binsel[0];
    Gprev += s_binsel[1];
  }
  const unsigned thr = prefix;
  const unsigned Rq = 256 - Gprev;
  const unsigned negfkey = ~__float_as_uint(NEGF);

  unsigned eqc = 0;
#pragma unroll
  for (int j = 0; j < 4; ++j) eqc += (s_key[i0 + j] == thr) ? 1u : 0u;
  unsigned esc = eqc;
  for (int off = 1; off < 64; off <<= 1) {
    unsigned v = __shfl_up(esc, off);
    if (lane >= off) esc += v;
  }
  if (lane == 63) s_wsum[wave] = esc;
  __syncthreads();
  unsigned eo = 0;
  for (int w = 0; w < wave; ++w) eo += s_wsum[w];
  unsigned rank = esc + eo - eqc;

#pragma unroll
  for (int j = 0; j < 4; ++j) {
    unsigned k = s_key[i0 + j];
    int outv = (k == negfkey) ? T_ : (i0 + j);
    if (k > thr) {
      unsigned slot = atomicAdd(&s_cnt, 1u);
      indices[t * TOPK_ + slot] = outv;
    } else if (k == thr) {
      if (rank < Rq) indices[t * TOPK_ + Gprev + rank] = outv;
      rank++;
    }
  }
}

// ================= MFMA gathered attention — LDS-union (s_p aliases s_vt) =================
#define SP_LD 257
#define PB_LD 264
__global__ __launch_bounds__(256) void attn_k(
    const short* __restrict__ sq, const short* __restrict__ skv,
    const int* __restrict__ indices, __hip_bfloat16* __restrict__ attn_out)
{
  __shared__ int s_ind[TOPK_];
  __shared__ __align__(16) short s_pb[H_ * PB_LD];
  __shared__ __align__(16) char s_un[64 * PB_LD * 2];  // 33792 B: s_p (16448 B) then s_vt
  float* s_p = (float*)s_un;
  short* s_vt = (short*)s_un;
  const int t = blockIdx.x, tid = threadIdx.x;
  const int wave = tid >> 6, lane = tid & 63;
  const int m0 = lane & 15, quad = lane >> 4;
  s_ind[tid] = indices[t * TOPK_ + tid];
  __syncthreads();

  {
    const int jb = wave * 64;
    int rows[4];
    const short* kvp[4];
#pragma unroll
    for (int j = 0; j < 4; ++j) {
      rows[j] = s_ind[jb + j * 16 + m0];
      kvp[j] = skv + rows[j] * 576 + quad * 8;
    }
    const short* qp = sq + ((long long)t * H_ + m0) * 576 + quad * 8;
    f32x4 qacc[4] = {};
    for (int ks = 0; ks < 18; ++ks) {
      const int k0 = ks * 32;
      bfrag_t aq = *(const bfrag_t*)(qp + k0);
#pragma unroll
      for (int j = 0; j < 4; ++j) {
        bfrag_t bq = *(const bfrag_t*)(kvp[j] + k0);
        qacc[j] = __builtin_amdgcn_mfma_f32_16x16x32_bf16(aq, bq, qacc[j], 0, 0, 0);
      }
    }
    const float scale = 0.07216878364870322f;
#pragma unroll
    for (int j = 0; j < 4; ++j) {
      int key = jb + j * 16 + m0;
      bool msk = (rows[j] == T_);
#pragma unroll
      for (int r = 0; r < 4; ++r)
        s_p[(quad * 4 + r) * SP_LD + key] = msk ? NEGF : qacc[j][r] * scale;
    }
  }
  __syncthreads();

  for (int h = wave * 4; h < wave * 4 + 4; ++h) {
    float* ph = s_p + h * SP_LD;
    float m = -3.4e38f;
    for (int j = lane; j < TOPK_; j += 64) m = fmaxf(m, ph[j]);
#pragma unroll
    for (int off = 32; off; off >>= 1) m = fmaxf(m, __shfl_xor(m, off));
    float sum = 0.f;
    for (int j = lane; j < TOPK_; j += 64) {
      float e = __expf(ph[j] - m);
      ph[j] = e; sum += e;
    }
    sum = wave_sum64(sum);
    float inv = 1.f / sum;
    for (int j = lane; j < TOPK_; j += 64) ph[j] *= inv;
  }
  __syncthreads();

#pragma unroll
  for (int h = 0; h < H_; ++h)
    s_pb[h * PB_LD + tid] = (short)__bfloat16_as_ushort(__float2bfloat16(s_p[h * SP_LD + tid]));
  __syncthreads();

  bfrag_t apf[8];
#pragma unroll
  for (int kk = 0; kk < 8; ++kk)
    apf[kk] = *(const bfrag_t*)(s_pb + m0 * PB_LD + kk * 32 + quad * 8);

  const int myrow = s_ind[tid];
  const short* vsrc = skv + myrow * 576;

  for (int c = 0; c < 8; ++c) {
    const int c0 = c * 64;
    __syncthreads();   // s_p (aliased) fully read; safe to overwrite s_vt
#pragma unroll
    for (int b = 0; b < 8; ++b) {
      bfrag_t v = *(const bfrag_t*)(vsrc + c0 + b * 8);
#pragma unroll
      for (int j = 0; j < 8; ++j)
        s_vt[(b * 8 + j) * PB_LD + tid] = v[j];
    }
    __syncthreads();
    const short* vb = s_vt + (wave * 16 + m0) * PB_LD + quad * 8;
    f32x4 oacc = {0.f, 0.f, 0.f, 0.f};
#pragma unroll
    for (int kk = 0; kk < 8; ++kk) {
      bfrag_t bv = *(const bfrag_t*)(vb + kk * 32);
      oacc = __builtin_amdgcn_mfma_f32_16x16x32_bf16(apf[kk], bv, oacc, 0, 0, 0);
    }
    const int col = c0 + wave * 16 + m0;
#pragma unroll
    for (int r = 0; r < 4; ++r)
      attn_out[((long long)t * H_ + quad * 4 + r) * 512 + col] = __float2bfloat16(oacc[r]);
  }
}

extern "C" void kernel_launch(void* const* d_in, const int* in_sizes, int n_in,
                              void* d_out, int out_size, void* d_ws, size_t ws_size,
                              hipStream_t stream) {
  const float* hidden  = (const float*)d_in[0];
  const float* cosb    = (const float*)d_in[1];
  const float* sinb    = (const float*)d_in[2];
  const int*   ks      = (const int*)d_in[3];
  const int*   ke      = (const int*)d_in[4];
  const float* w_qa    = (const float*)d_in[5];
  const float* g_qa    = (const float*)d_in[6];
  const float* w_qb    = (const float*)d_in[7];
  const float* w_kva   = (const float*)d_in[8];
  const float* g_kva   = (const float*)d_in[9];
  const float* w_kvb   = (const float*)d_in[10];
  const float* w_o     = (const float*)d_in[11];
  const float* i_wqb   = (const float*)d_in[12];
  const float* i_wk    = (const float*)d_in[13];
  const float* i_ln_w  = (const float*)d_in[14];
  const float* i_ln_b  = (const float*)d_in[15];
  const float* i_wproj = (const float*)d_in[16];
  float* out = (float*)d_out;
  (void)in_sizes; (void)n_in; (void)out_size; (void)ws_size;

  // ---- workspace (bytes), lifetime-overlapped (layout verified R6) ----
  char* ws = (char*)d_ws;
  __hip_bfloat16* hid_hi  = (__hip_bfloat16*)(ws + 0);
  __hip_bfloat16* hid_lo  = (__hip_bfloat16*)(ws + 4194304);
  float*          q_lat   = (float*)(ws + 8388608);
  __hip_bfloat16* qi_hi   = (__hip_bfloat16*)(ws + 8388608);    // over dead q_lat
  __hip_bfloat16* qlat_hi = (__hip_bfloat16*)(ws + 14680064);
  __hip_bfloat16* qlat_lo = (__hip_bfloat16*)(ws + 17825792);
  float*          qi      = (float*)(ws + 20971520);
  float*          kib     = (float*)(ws + 29360128);
  float*          wbuf    = (float*)(ws + 29884416);
  float*          ckv     = (float*)(ws + 29949952);
  __hip_bfloat16* qi_lo   = (__hip_bfloat16*)(ws + 29949952);   // over dead ckv
  __hip_bfloat16* ki_hi   = (__hip_bfloat16*)(ws + 34144256);
  __hip_bfloat16* ki_lo   = (__hip_bfloat16*)(ws + 34406400);
  __hip_bfloat16* sq_bf   = (__hip_bfloat16*)(ws + 0);
  __hip_bfloat16* o_bf    = (__hip_bfloat16*)(ws + 0);
  __hip_bfloat16* W       = (__hip_bfloat16*)(ws + 37748736);
  __hip_bfloat16* skv_bf  = (__hip_bfloat16*)(ws + 47185920);
  int*            idxb    = (int*)(ws + 48366720);
  __hip_bfloat16* E       = (__hip_bfloat16*)(ws + 49415296);

  dim3 blk(256);
  const short* Ws = (const short*)W;
  const short* Es = (const short*)E;

  decomp_k<<<2048, blk, 0, stream>>>(hidden, hid_hi, hid_lo, 524288);

  decomp_k<<<3072, blk, 0, stream>>>(w_qa, W, E, 786432);
  gemm3_k<<<dim3(12, 8), blk, 0, stream>>>(
      (const short*)hid_hi, (const short*)hid_lo, HID_, Ws, Es, HID_, q_lat, LQ_, LQ_, HID_);
  rms_inplace_k<<<T_, blk, 0, stream>>>(q_lat, g_qa, LQ_);

  cast_pad_k<<<1280, blk, 0, stream>>>(w_kva, W, 576, 512, 640);
  gemm_bf_k<float><<<dim3(5, 8, 1), blk, 0, stream>>>(
      (const short*)hid_hi, HID_, 0, Ws, HID_, 0, ckv, 576, 0, 576, HID_);
  skv_build_k<<<T_ + 1, blk, 0, stream>>>(ckv, g_kva, cosb, sinb, skv_bf);

  decomp_k<<<1536, blk, 0, stream>>>(q_lat, qlat_hi, qlat_lo, 393216);

  decomp_k<<<3072, blk, 0, stream>>>(i_wqb, W, E, 786432);
  gemm3_k<<<dim3(16, 8), blk, 0, stream>>>(
      (const short*)qlat_hi, (const short*)qlat_lo, LQ_, Ws, Es, LQ_, qi, HI_ * DI_, HI_ * DI_, LQ_);
  rope_qi_k<<<T_ * HI_, dim3(64), 0, stream>>>(qi, cosb, sinb);
  decomp_k<<<2048, blk, 0, stream>>>(qi, qi_hi, qi_lo, 524288);

  decomp_k<<<256, blk, 0, stream>>>(i_wk, W, E, 65536);
  gemm3_k<<<dim3(1, 8), blk, 0, stream>>>(
      (const short*)hid_hi, (const short*)hid_lo, HID_, Ws, Es, HID_, kib, DI_, DI_, HID_);
  ki_ln_rope_k<<<T_, dim3(128), 0, stream>>>(kib, i_ln_w, i_ln_b, cosb, sinb);
  decomp_k<<<128, blk, 0, stream>>>(kib, ki_hi, ki_lo, 32768);

  wproj_k<<<256, blk, 0, stream>>>(hidden, i_wproj, wbuf);

  score_topk_k<<<T_, blk, 0, stream>>>(
      (const short*)qi_hi, (const short*)qi_lo, (const short*)ki_hi, (const short*)ki_lo,
      wbuf, ks, ke, idxb);

  cast_bf16_k<<<4608, blk, 0, stream>>>(w_qb, W, 1179648);
  gemm_bf_k<__hip_bfloat16><<<dim3(24, 8, 1), blk, 0, stream>>>(
      (const short*)qlat_hi, LQ_, 0, Ws, LQ_, 0, (__hip_bfloat16*)E, H_ * DQ_, 0, H_ * DQ_, LQ_);
  rope_q_sq_k<<<T_ * H_, dim3(64), 0, stream>>>(E, cosb, sinb, sq_bf);

  wkn_t_k<<<dim3(2, 8, 16), blk, 0, stream>>>(w_kvb, W);
  gemm_bf_k<__hip_bfloat16><<<dim3(4, 8, 16), blk, 0, stream>>>(
      Es, H_ * DQ_, 192, Ws, DI_, 65536, sq_bf, H_ * 576, 576, LKV_, DN_);

  attn_k<<<T_, blk, 0, stream>>>((const short*)sq_bf, (const short*)skv_bf, idxb, E);

  wv_cast_k<<<4096, blk, 0, stream>>>(w_kvb, W);
  gemm_bf_k<__hip_bfloat16><<<dim3(1, 8, 16), blk, 0, stream>>>(
      Es, H_ * LKV_, 512, Ws, LKV_, 65536, o_bf, H_ * DV_, 128, DV_, LKV_);

  cast_bf16_k<<<4096, blk, 0, stream>>>(w_o, W, 1048576);
  gemm_bf_k<float><<<dim3(16, 8, 1), blk, 0, stream>>>(
      (const short*)o_bf, H_ * DV_, 0, Ws, H_ * DV_, 0, out, HID_, 0, HID_, H_ * DV_);
}